// Round 2
// baseline (2417.428 us; speedup 1.0000x reference)
//
#include <hip/hip_runtime.h>
#include <cstdint>
#include <cstddef>

#define HD 128  // hidden channels

static inline int ceil_div(int a, int b) { return (a + b - 1) / b; }
static inline int imax(int a, int b) { return a > b ? a : b; }

// ============ bucket sort of edges (64 dst-nodes per bucket) ============
// Edge entries packed as u32: (src16 << 6) | local_dst6. Requires ids < 65536.

__global__ __launch_bounds__(256) void k_bhist(const int* __restrict__ ei, int nE,
                                               int* __restrict__ histT, int nbT,
                                               int* __restrict__ histS, int nbS) {
  __shared__ int h[1600];
  int nb = nbT + nbS;
  for (int i = threadIdx.x; i < nb; i += 256) h[i] = 0;
  __syncthreads();
  int stride = gridDim.x * 256;
  for (int e = blockIdx.x * 256 + threadIdx.x; e < nE; e += stride) {
    int s = ei[e];
    int t = ei[nE + e];
    atomicAdd(&h[t >> 6], 1);
    atomicAdd(&h[nbT + (s >> 6)], 1);
  }
  __syncthreads();
  for (int i = threadIdx.x; i < nb; i += 256) {
    int v = h[i];
    if (v) {
      if (i < nbT) atomicAdd(&histT[i], v);
      else atomicAdd(&histS[i - nbT], v);
    }
  }
}

// grid=2 blocks x 1024; n <= 1024. off[i]=exclusive scan, off[n]=total,
// hist[i] overwritten with cursor start (=off[i]).
__global__ __launch_bounds__(1024) void k_bscan(int* __restrict__ histA, int* __restrict__ offA, int nA,
                                                int* __restrict__ histB, int* __restrict__ offB, int nB) {
  int* hist = blockIdx.x ? histB : histA;
  int* off = blockIdx.x ? offB : offA;
  int n = blockIdx.x ? nB : nA;
  __shared__ int wsum[16];
  int tid = threadIdx.x;
  int lane = tid & 63;
  int wid = tid >> 6;
  int v = (tid < n) ? hist[tid] : 0;
  int x = v;
#pragma unroll
  for (int d = 1; d < 64; d <<= 1) {
    int y = __shfl_up(x, d, 64);
    if (lane >= d) x += y;
  }
  if (lane == 63) wsum[wid] = x;
  __syncthreads();
  if (wid == 0) {
    int s = (lane < 16) ? wsum[lane] : 0;
#pragma unroll
    for (int d = 1; d < 16; d <<= 1) {
      int y = __shfl_up(s, d, 64);
      if (lane >= d) s += y;
    }
    if (lane < 16) wsum[lane] = s;
  }
  __syncthreads();
  int wofs = (wid > 0) ? wsum[wid - 1] : 0;
  int exc = wofs + x - v;
  if (tid < n) {
    off[tid] = exc;
    hist[tid] = exc;  // cursor
  }
  if (tid == 0) off[n] = wsum[15];
}

#define SC_CH 2048  // edges per scatter block (256 thr x 8)
__global__ __launch_bounds__(256) void k_bscatter(const int* __restrict__ ei, int nE,
                                                  int* __restrict__ curT, int nbT,
                                                  unsigned* __restrict__ ebufT,
                                                  int* __restrict__ curS, int nbS,
                                                  unsigned* __restrict__ ebufS) {
  __shared__ unsigned epk[SC_CH];
  __shared__ int cntT[800], baseT[800], cntS[800], baseS[800];
  int tid = threadIdx.x;
  int e0 = blockIdx.x * SC_CH;
  for (int i = tid; i < nbT; i += 256) cntT[i] = 0;
  for (int i = tid; i < nbS; i += 256) cntS[i] = 0;
  for (int i = tid; i < SC_CH; i += 256) {
    int e = e0 + i;
    epk[i] = (e < nE) ? (((unsigned)ei[e] << 16) | (unsigned)ei[nE + e]) : 0xFFFFFFFFu;
  }
  __syncthreads();
  int rT[8], rS[8];
#pragma unroll
  for (int j = 0; j < 8; ++j) {
    int i = tid * 8 + j;
    unsigned p = epk[i];
    if (p != 0xFFFFFFFFu) {
      int t = (int)(p & 0xFFFFu);
      int s = (int)(p >> 16);
      rT[j] = atomicAdd(&cntT[t >> 6], 1);
      rS[j] = atomicAdd(&cntS[s >> 6], 1);
    }
  }
  __syncthreads();
  for (int b = tid; b < nbT; b += 256) baseT[b] = cntT[b] ? atomicAdd(&curT[b], cntT[b]) : 0;
  for (int b = tid; b < nbS; b += 256) baseS[b] = cntS[b] ? atomicAdd(&curS[b], cntS[b]) : 0;
  __syncthreads();
#pragma unroll
  for (int j = 0; j < 8; ++j) {
    int i = tid * 8 + j;
    unsigned p = epk[i];
    if (p != 0xFFFFFFFFu) {
      unsigned t = p & 0xFFFFu;
      unsigned s = p >> 16;
      ebufT[baseT[t >> 6] + rT[j]] = (s << 6) | (t & 63u);
      ebufS[baseS[s >> 6] + rS[j]] = (t << 6) | (s & 63u);
    }
  }
}

// ============ scatter-mean via LDS accumulation (block = one 64-node bucket) ============
__global__ __launch_bounds__(512) void k_agg_lds(const float* __restrict__ xsrc,
                                                 const int* __restrict__ smap,
                                                 const int* __restrict__ boff,
                                                 const unsigned* __restrict__ ebuf,
                                                 float* __restrict__ agg, int ndst) {
  __shared__ float acc[64 * HD];
  __shared__ int cnt[64];
  int tid = threadIdx.x;
  for (int i = tid; i < 64 * HD; i += 512) acc[i] = 0.f;
  if (tid < 64) cnt[tid] = 0;
  __syncthreads();
  int b = blockIdx.x;
  int beg = boff[b], end = boff[b + 1];
  int lane = tid & 63;
  int wid = tid >> 6;
  for (int k = beg + wid * 2; k < end; k += 16) {
    unsigned e0 = ebuf[k];
    int s0 = (int)(e0 >> 6), lt0 = (int)(e0 & 63u);
    if (smap) s0 = smap[s0];
    float2 v0 = ((const float2*)xsrc)[(size_t)s0 * 64 + lane];
    bool two = (k + 1 < end);
    int s1 = 0, lt1 = 0;
    float2 v1 = make_float2(0.f, 0.f);
    if (two) {
      unsigned e1 = ebuf[k + 1];
      s1 = (int)(e1 >> 6);
      lt1 = (int)(e1 & 63u);
      if (smap) s1 = smap[s1];
      v1 = ((const float2*)xsrc)[(size_t)s1 * 64 + lane];
    }
    if (lane == 0) atomicAdd(&cnt[lt0], 1);
    atomicAdd(&acc[lt0 * HD + lane * 2], v0.x);
    atomicAdd(&acc[lt0 * HD + lane * 2 + 1], v0.y);
    if (two) {
      if (lane == 0) atomicAdd(&cnt[lt1], 1);
      atomicAdd(&acc[lt1 * HD + lane * 2], v1.x);
      atomicAdd(&acc[lt1 * HD + lane * 2 + 1], v1.y);
    }
  }
  __syncthreads();
  int node0 = b << 6;
  float2* a2 = (float2*)acc;
  for (int i = tid; i < 64 * 64; i += 512) {
    int row = i >> 6;
    int c = i & 63;
    int node = node0 + row;
    if (node < ndst) {
      int kk = cnt[row];
      float inv = kk ? 1.f / (float)kk : 0.f;
      float2 v = a2[i];
      ((float2*)agg)[(size_t)node * 64 + c] = make_float2(v.x * inv, v.y * inv);
    }
  }
}

// ---------------- weight prep: wT[k][j] = concat(wl, wr) transposed ----------------
__global__ void k_build_wT(const float* __restrict__ wl, const float* __restrict__ wr,
                           float* __restrict__ wT) {
  int idx = blockIdx.x * blockDim.x + threadIdx.x;
  if (idx >= 256 * HD) return;
  int k = idx >> 7;
  int j = idx & (HD - 1);
  wT[idx] = (k < HD) ? wl[j * HD + k] : wr[j * HD + (k - HD)];
}

// ---------------- fused GEMM + bias + L2-norm + (leaky | residual) ----------------
__global__ __launch_bounds__(256) void k_gemm_fused(
    const float* __restrict__ agg,   // [n,128]
    const float* __restrict__ xdst,  // base table [*,128]
    const int* __restrict__ xidx,    // may be null: row -> xdst row
    const float* __restrict__ wT,    // [256][128] (k-major)
    const float* __restrict__ bias,  // [128]
    const float* __restrict__ resid, // may be null, [n,128] (added AFTER norm)
    float* __restrict__ out, int n, int leaky) {
  __shared__ float As[32][256];
  int t = threadIdx.x;
  int base = blockIdx.x * 32;

  for (int f = t; f < 32 * 64; f += 256) {
    int r = f >> 6;
    int q = f & 63;
    int row = base + r;
    float4 v = make_float4(0.f, 0.f, 0.f, 0.f);
    if (row < n) {
      if (q < 32) {
        v = ((const float4*)(agg + (size_t)row * HD))[q];
      } else {
        int xr = xidx ? xidx[row] : row;
        v = ((const float4*)(xdst + (size_t)xr * HD))[q - 32];
      }
    }
    ((float4*)&As[0][0])[f] = v;
  }
  __syncthreads();

  int c = t & 63;
  int h = t >> 6;

  float acc[8][2];
  float b0 = bias[c];
  float b1 = bias[c + 64];
#pragma unroll
  for (int r = 0; r < 8; ++r) {
    acc[r][0] = b0;
    acc[r][1] = b1;
  }

  for (int k = 0; k < 256; k += 4) {
    float w0[4], w1[4];
#pragma unroll
    for (int kk = 0; kk < 4; ++kk) {
      w0[kk] = wT[(k + kk) * HD + c];
      w1[kk] = wT[(k + kk) * HD + c + 64];
    }
#pragma unroll
    for (int r = 0; r < 8; ++r) {
      float4 a = *((const float4*)&As[h * 8 + r][k]);
      acc[r][0] += a.x * w0[0] + a.y * w0[1] + a.z * w0[2] + a.w * w0[3];
      acc[r][1] += a.x * w1[0] + a.y * w1[1] + a.z * w1[2] + a.w * w1[3];
    }
  }

#pragma unroll
  for (int r = 0; r < 8; ++r) {
    int row = base + h * 8 + r;
    float ss = acc[r][0] * acc[r][0] + acc[r][1] * acc[r][1];
#pragma unroll
    for (int ofs = 32; ofs > 0; ofs >>= 1) ss += __shfl_xor(ss, ofs, 64);
    float nrm = sqrtf(ss);
    float inv = 1.0f / fmaxf(nrm, 1e-12f);
    float v0 = acc[r][0] * inv;
    float v1 = acc[r][1] * inv;
    if (leaky) {
      v0 = (v0 > 0.f) ? v0 : 0.01f * v0;
      v1 = (v1 > 0.f) ? v1 : 0.01f * v1;
    }
    if (row < n) {
      if (resid) {
        v0 += resid[(size_t)row * HD + c];
        v1 += resid[(size_t)row * HD + c + 64];
      }
      out[(size_t)row * HD + c] = v0;
      out[(size_t)row * HD + c + 64] = v1;
    }
  }
}

// ---------------- classifier ----------------
__global__ __launch_bounds__(256) void k_classifier(
    const int* __restrict__ eli, int nL,
    const float* __restrict__ h3s, const float* __restrict__ h3t,
    float* __restrict__ out) {
  int w = (int)((blockIdx.x * 256 + threadIdx.x) >> 6);
  int lane = threadIdx.x & 63;
  if (w >= nL) return;
  int s = eli[w];
  int t = eli[nL + w];
  float2 a = ((const float2*)h3s)[(size_t)s * 64 + lane];
  float2 b = ((const float2*)h3t)[(size_t)t * 64 + lane];
  float p = a.x * b.x + a.y * b.y;
#pragma unroll
  for (int ofs = 32; ofs > 0; ofs >>= 1) p += __shfl_xor(p, ofs, 64);
  if (lane == 0) out[w] = p;
}

extern "C" void kernel_launch(void* const* d_in, const int* in_sizes, int n_in,
                              void* d_out, int out_size, void* d_ws, size_t ws_size,
                              hipStream_t stream) {
  (void)n_in;
  (void)out_size;
  const int* snid = (const int*)d_in[0];
  const int* tnid = (const int*)d_in[1];
  const int* ei = (const int*)d_in[2];
  const int* eli = (const int*)d_in[3];
  const float* semb = (const float*)d_in[4];
  const float* temb = (const float*)d_in[5];
  const float* w1l_bt = (const float*)d_in[6];
  const float* w1r_bt = (const float*)d_in[7];
  const float* w1l_tb = (const float*)d_in[8];
  const float* w1r_tb = (const float*)d_in[9];
  const float* w2l_bt = (const float*)d_in[10];
  const float* w2r_bt = (const float*)d_in[11];
  const float* w2l_tb = (const float*)d_in[12];
  const float* w2r_tb = (const float*)d_in[13];
  const float* b1_bt = (const float*)d_in[14];
  const float* b1_tb = (const float*)d_in[15];
  const float* b2_bt = (const float*)d_in[16];
  const float* b2_tb = (const float*)d_in[17];

  const int NS_ = in_sizes[0];
  const int NT_ = in_sizes[1];
  const int nE = in_sizes[2] / 2;
  const int nL = in_sizes[3] / 2;
  float* out = (float*)d_out;

  if (NS_ > 65535 || NT_ > 65535) return;  // packing assumption

  const int nbT = (NT_ + 63) >> 6;
  const int nbS = (NS_ + 63) >> 6;
  if (nbT > 800 || nbS > 800 || nbT + nbS > 1600) return;

  char* ws = (char*)d_ws;
  size_t o = 0;
  auto alloc = [&](size_t bytes) -> void* {
    void* p = ws + o;
    o = (o + bytes + 255) & ~(size_t)255;
    return p;
  };
  int* boffT = (int*)alloc(((size_t)nbT + 1) * 4);
  int* bcurT = (int*)alloc((size_t)nbT * 4);
  int* boffS = (int*)alloc(((size_t)nbS + 1) * 4);
  int* bcurS = (int*)alloc((size_t)nbS * 4);
  unsigned* ebufT = (unsigned*)alloc((size_t)nE * 4);
  unsigned* ebufS = (unsigned*)alloc((size_t)nE * 4);
  float* wT1 = (float*)alloc(256 * HD * 4);
  float* wT2 = (float*)alloc(256 * HD * 4);
  float* wT3 = (float*)alloc(256 * HD * 4);
  float* wT4 = (float*)alloc(256 * HD * 4);
  int nmax = imax(NS_, NT_);
  float* agg = (float*)alloc((size_t)nmax * HD * 4);
  float* h1s = (float*)alloc((size_t)NS_ * HD * 4);
  float* h1t = (float*)alloc((size_t)NT_ * HD * 4);
  float* h3s = (float*)alloc((size_t)NS_ * HD * 4);
  float* h3t = (float*)alloc((size_t)NT_ * HD * 4);
  if (o > ws_size) return;

  // ---- bucket sort (both directions) ----
  hipMemsetAsync(bcurT, 0, (size_t)nbT * 4, stream);
  hipMemsetAsync(bcurS, 0, (size_t)nbS * 4, stream);
  k_bhist<<<64, 256, 0, stream>>>(ei, nE, bcurT, nbT, bcurS, nbS);
  k_bscan<<<2, 1024, 0, stream>>>(bcurT, boffT, nbT, bcurS, boffS, nbS);
  k_bscatter<<<ceil_div(nE, SC_CH), 256, 0, stream>>>(ei, nE, bcurT, nbT, ebufT,
                                                      bcurS, nbS, ebufS);

  // ---- weight prep ----
  int wgrid = ceil_div(256 * HD, 256);
  k_build_wT<<<wgrid, 256, 0, stream>>>(w1l_bt, w1r_bt, wT1);
  k_build_wT<<<wgrid, 256, 0, stream>>>(w1l_tb, w1r_tb, wT2);
  k_build_wT<<<wgrid, 256, 0, stream>>>(w2l_bt, w2r_bt, wT3);
  k_build_wT<<<wgrid, 256, 0, stream>>>(w2l_tb, w2r_tb, wT4);

  // ---- layer 1 ----
  k_agg_lds<<<nbT, 512, 0, stream>>>(semb, snid, boffT, ebufT, agg, NT_);
  k_gemm_fused<<<ceil_div(NT_, 32), 256, 0, stream>>>(agg, temb, tnid, wT1, b1_bt, nullptr,
                                                      h1t, NT_, 1);
  k_agg_lds<<<nbS, 512, 0, stream>>>(temb, tnid, boffS, ebufS, agg, NS_);
  k_gemm_fused<<<ceil_div(NS_, 32), 256, 0, stream>>>(agg, semb, snid, wT2, b1_tb, nullptr,
                                                      h1s, NS_, 1);

  // ---- layer 2 ----
  k_agg_lds<<<nbT, 512, 0, stream>>>(h1s, nullptr, boffT, ebufT, agg, NT_);
  k_gemm_fused<<<ceil_div(NT_, 32), 256, 0, stream>>>(agg, h1t, nullptr, wT3, b2_bt, h1t,
                                                      h3t, NT_, 0);
  k_agg_lds<<<nbS, 512, 0, stream>>>(h1t, nullptr, boffS, ebufS, agg, NS_);
  k_gemm_fused<<<ceil_div(NS_, 32), 256, 0, stream>>>(agg, h1s, nullptr, wT4, b2_tb, h1s,
                                                      h3s, NS_, 0);

  // ---- classifier ----
  k_classifier<<<ceil_div(nL, 4), 256, 0, stream>>>(eli, nL, h3s, h3t, out);
}

// Round 3
// 578.520 us; speedup vs baseline: 4.1786x; 4.1786x over previous
//
#include <hip/hip_runtime.h>
#include <cstdint>
#include <cstddef>

#define HD 128  // hidden channels

static inline int ceil_div(int a, int b) { return (a + b - 1) / b; }
static inline int imax(int a, int b) { return a > b ? a : b; }

// ============ bucket sort of edges (64 dst-nodes per bucket) ============
// Edge entries packed as u32: (src16 << 6) | local_dst6. Requires ids < 65536.

__global__ __launch_bounds__(256) void k_bhist(const int* __restrict__ ei, int nE,
                                               int* __restrict__ histT, int nbT,
                                               int* __restrict__ histS, int nbS) {
  __shared__ int h[1600];
  int nb = nbT + nbS;
  for (int i = threadIdx.x; i < nb; i += 256) h[i] = 0;
  __syncthreads();
  int stride = gridDim.x * 256;
  for (int e = blockIdx.x * 256 + threadIdx.x; e < nE; e += stride) {
    int s = ei[e];
    int t = ei[nE + e];
    atomicAdd(&h[t >> 6], 1);
    atomicAdd(&h[nbT + (s >> 6)], 1);
  }
  __syncthreads();
  for (int i = threadIdx.x; i < nb; i += 256) {
    int v = h[i];
    if (v) {
      if (i < nbT) atomicAdd(&histT[i], v);
      else atomicAdd(&histS[i - nbT], v);
    }
  }
}

// grid=2 blocks x 1024; n <= 1024. off[i]=exclusive scan, off[n]=total,
// hist[i] overwritten with cursor start (=off[i]).
__global__ __launch_bounds__(1024) void k_bscan(int* __restrict__ histA, int* __restrict__ offA, int nA,
                                                int* __restrict__ histB, int* __restrict__ offB, int nB) {
  int* hist = blockIdx.x ? histB : histA;
  int* off = blockIdx.x ? offB : offA;
  int n = blockIdx.x ? nB : nA;
  __shared__ int wsum[16];
  int tid = threadIdx.x;
  int lane = tid & 63;
  int wid = tid >> 6;
  int v = (tid < n) ? hist[tid] : 0;
  int x = v;
#pragma unroll
  for (int d = 1; d < 64; d <<= 1) {
    int y = __shfl_up(x, d, 64);
    if (lane >= d) x += y;
  }
  if (lane == 63) wsum[wid] = x;
  __syncthreads();
  if (wid == 0) {
    int s = (lane < 16) ? wsum[lane] : 0;
#pragma unroll
    for (int d = 1; d < 16; d <<= 1) {
      int y = __shfl_up(s, d, 64);
      if (lane >= d) s += y;
    }
    if (lane < 16) wsum[lane] = s;
  }
  __syncthreads();
  int wofs = (wid > 0) ? wsum[wid - 1] : 0;
  int exc = wofs + x - v;
  if (tid < n) {
    off[tid] = exc;
    hist[tid] = exc;  // cursor
  }
  if (tid == 0) off[n] = wsum[15];
}

#define SC_CH 2048  // edges per scatter block (256 thr x 8)
__global__ __launch_bounds__(256) void k_bscatter(const int* __restrict__ ei, int nE,
                                                  int* __restrict__ curT, int nbT,
                                                  unsigned* __restrict__ ebufT,
                                                  int* __restrict__ curS, int nbS,
                                                  unsigned* __restrict__ ebufS) {
  __shared__ unsigned epk[SC_CH];
  __shared__ int cntT[800], baseT[800], cntS[800], baseS[800];
  int tid = threadIdx.x;
  int e0 = blockIdx.x * SC_CH;
  for (int i = tid; i < nbT; i += 256) cntT[i] = 0;
  for (int i = tid; i < nbS; i += 256) cntS[i] = 0;
  for (int i = tid; i < SC_CH; i += 256) {
    int e = e0 + i;
    epk[i] = (e < nE) ? (((unsigned)ei[e] << 16) | (unsigned)ei[nE + e]) : 0xFFFFFFFFu;
  }
  __syncthreads();
  int rT[8], rS[8];
#pragma unroll
  for (int j = 0; j < 8; ++j) {
    int i = tid * 8 + j;
    unsigned p = epk[i];
    if (p != 0xFFFFFFFFu) {
      int t = (int)(p & 0xFFFFu);
      int s = (int)(p >> 16);
      rT[j] = atomicAdd(&cntT[t >> 6], 1);
      rS[j] = atomicAdd(&cntS[s >> 6], 1);
    }
  }
  __syncthreads();
  for (int b = tid; b < nbT; b += 256) baseT[b] = cntT[b] ? atomicAdd(&curT[b], cntT[b]) : 0;
  for (int b = tid; b < nbS; b += 256) baseS[b] = cntS[b] ? atomicAdd(&curS[b], cntS[b]) : 0;
  __syncthreads();
#pragma unroll
  for (int j = 0; j < 8; ++j) {
    int i = tid * 8 + j;
    unsigned p = epk[i];
    if (p != 0xFFFFFFFFu) {
      unsigned t = p & 0xFFFFu;
      unsigned s = p >> 16;
      ebufT[baseT[t >> 6] + rT[j]] = (s << 6) | (t & 63u);
      ebufS[baseS[s >> 6] + rS[j]] = (t << 6) | (s & 63u);
    }
  }
}

// ============ per-bucket counting sort -> per-node CSR ============
// one block per bucket; 64 bins; writes adj (src ids, per-node contiguous)
// and noff[node] (global per-node offsets). noff[ndst] = nE set by block 0.
__global__ __launch_bounds__(256) void k_bsort(const unsigned* __restrict__ ebuf,
                                               const int* __restrict__ boff,
                                               int* __restrict__ noff,
                                               int* __restrict__ adj,
                                               int ndst, int nE) {
  __shared__ int cnt[64];
  __shared__ int pos[64];
  int b = blockIdx.x;
  int tid = threadIdx.x;
  if (tid < 64) cnt[tid] = 0;
  __syncthreads();
  int beg = boff[b], end = boff[b + 1];
  for (int k = beg + tid; k < end; k += 256) {
    atomicAdd(&cnt[ebuf[k] & 63u], 1);
  }
  __syncthreads();
  if (tid < 64) {
    int v = cnt[tid];
    int x = v;
#pragma unroll
    for (int d = 1; d < 64; d <<= 1) {
      int y = __shfl_up(x, d, 64);
      if (tid >= d) x += y;
    }
    int start = beg + x - v;
    pos[tid] = start;
    int node = (b << 6) + tid;
    if (node < ndst) noff[node] = start;
  }
  __syncthreads();
  for (int k = beg + tid; k < end; k += 256) {
    unsigned e = ebuf[k];
    int p = atomicAdd(&pos[e & 63u], 1);
    adj[p] = (int)(e >> 6);
  }
  if (b == 0 && tid == 0) noff[ndst] = nE;
}

// ============ scatter-mean (gather form over per-node CSR) ============
// one wave per destination node; lane holds 2 channels (float2)
__global__ __launch_bounds__(256) void k_agg_mean(
    const float* __restrict__ xsrc, const int* __restrict__ smap,
    const int* __restrict__ noff, const int* __restrict__ adj,
    float* __restrict__ agg, int ndst) {
  int gw = (int)((blockIdx.x * 256 + threadIdx.x) >> 6);
  int lane = threadIdx.x & 63;
  if (gw >= ndst) return;
  int beg = noff[gw], end = noff[gw + 1];
  float ax = 0.f, ay = 0.f;
  int k = beg;
  for (; k + 1 < end; k += 2) {  // 2 loads in flight
    int n0 = adj[k];
    int n1 = adj[k + 1];
    if (smap) {
      n0 = smap[n0];
      n1 = smap[n1];
    }
    float2 v0 = ((const float2*)xsrc)[(size_t)n0 * 64 + lane];
    float2 v1 = ((const float2*)xsrc)[(size_t)n1 * 64 + lane];
    ax += v0.x + v1.x;
    ay += v0.y + v1.y;
  }
  if (k < end) {
    int n0 = adj[k];
    if (smap) n0 = smap[n0];
    float2 v0 = ((const float2*)xsrc)[(size_t)n0 * 64 + lane];
    ax += v0.x;
    ay += v0.y;
  }
  int deg = end - beg;
  float inv = deg ? 1.0f / (float)deg : 0.0f;
  ((float2*)agg)[(size_t)gw * 64 + lane] = make_float2(ax * inv, ay * inv);
}

// ---------------- weight prep: wT[k][j] = concat(wl, wr) transposed ----------------
__global__ void k_build_wT(const float* __restrict__ wl, const float* __restrict__ wr,
                           float* __restrict__ wT) {
  int idx = blockIdx.x * blockDim.x + threadIdx.x;
  if (idx >= 256 * HD) return;
  int k = idx >> 7;
  int j = idx & (HD - 1);
  wT[idx] = (k < HD) ? wl[j * HD + k] : wr[j * HD + (k - HD)];
}

// ---------------- fused GEMM + bias + L2-norm + (leaky | residual) ----------------
__global__ __launch_bounds__(256) void k_gemm_fused(
    const float* __restrict__ agg,   // [n,128]
    const float* __restrict__ xdst,  // base table [*,128]
    const int* __restrict__ xidx,    // may be null: row -> xdst row
    const float* __restrict__ wT,    // [256][128] (k-major)
    const float* __restrict__ bias,  // [128]
    const float* __restrict__ resid, // may be null, [n,128] (added AFTER norm)
    float* __restrict__ out, int n, int leaky) {
  __shared__ float As[32][256];
  int t = threadIdx.x;
  int base = blockIdx.x * 32;

  for (int f = t; f < 32 * 64; f += 256) {
    int r = f >> 6;
    int q = f & 63;
    int row = base + r;
    float4 v = make_float4(0.f, 0.f, 0.f, 0.f);
    if (row < n) {
      if (q < 32) {
        v = ((const float4*)(agg + (size_t)row * HD))[q];
      } else {
        int xr = xidx ? xidx[row] : row;
        v = ((const float4*)(xdst + (size_t)xr * HD))[q - 32];
      }
    }
    ((float4*)&As[0][0])[f] = v;
  }
  __syncthreads();

  int c = t & 63;
  int h = t >> 6;

  float acc[8][2];
  float b0 = bias[c];
  float b1 = bias[c + 64];
#pragma unroll
  for (int r = 0; r < 8; ++r) {
    acc[r][0] = b0;
    acc[r][1] = b1;
  }

  for (int k = 0; k < 256; k += 4) {
    float w0[4], w1[4];
#pragma unroll
    for (int kk = 0; kk < 4; ++kk) {
      w0[kk] = wT[(k + kk) * HD + c];
      w1[kk] = wT[(k + kk) * HD + c + 64];
    }
#pragma unroll
    for (int r = 0; r < 8; ++r) {
      float4 a = *((const float4*)&As[h * 8 + r][k]);
      acc[r][0] += a.x * w0[0] + a.y * w0[1] + a.z * w0[2] + a.w * w0[3];
      acc[r][1] += a.x * w1[0] + a.y * w1[1] + a.z * w1[2] + a.w * w1[3];
    }
  }

#pragma unroll
  for (int r = 0; r < 8; ++r) {
    int row = base + h * 8 + r;
    float ss = acc[r][0] * acc[r][0] + acc[r][1] * acc[r][1];
#pragma unroll
    for (int ofs = 32; ofs > 0; ofs >>= 1) ss += __shfl_xor(ss, ofs, 64);
    float nrm = sqrtf(ss);
    float inv = 1.0f / fmaxf(nrm, 1e-12f);
    float v0 = acc[r][0] * inv;
    float v1 = acc[r][1] * inv;
    if (leaky) {
      v0 = (v0 > 0.f) ? v0 : 0.01f * v0;
      v1 = (v1 > 0.f) ? v1 : 0.01f * v1;
    }
    if (row < n) {
      if (resid) {
        v0 += resid[(size_t)row * HD + c];
        v1 += resid[(size_t)row * HD + c + 64];
      }
      out[(size_t)row * HD + c] = v0;
      out[(size_t)row * HD + c + 64] = v1;
    }
  }
}

// ---------------- classifier ----------------
__global__ __launch_bounds__(256) void k_classifier(
    const int* __restrict__ eli, int nL,
    const float* __restrict__ h3s, const float* __restrict__ h3t,
    float* __restrict__ out) {
  int w = (int)((blockIdx.x * 256 + threadIdx.x) >> 6);
  int lane = threadIdx.x & 63;
  if (w >= nL) return;
  int s = eli[w];
  int t = eli[nL + w];
  float2 a = ((const float2*)h3s)[(size_t)s * 64 + lane];
  float2 b = ((const float2*)h3t)[(size_t)t * 64 + lane];
  float p = a.x * b.x + a.y * b.y;
#pragma unroll
  for (int ofs = 32; ofs > 0; ofs >>= 1) p += __shfl_xor(p, ofs, 64);
  if (lane == 0) out[w] = p;
}

extern "C" void kernel_launch(void* const* d_in, const int* in_sizes, int n_in,
                              void* d_out, int out_size, void* d_ws, size_t ws_size,
                              hipStream_t stream) {
  (void)n_in;
  (void)out_size;
  const int* snid = (const int*)d_in[0];
  const int* tnid = (const int*)d_in[1];
  const int* ei = (const int*)d_in[2];
  const int* eli = (const int*)d_in[3];
  const float* semb = (const float*)d_in[4];
  const float* temb = (const float*)d_in[5];
  const float* w1l_bt = (const float*)d_in[6];
  const float* w1r_bt = (const float*)d_in[7];
  const float* w1l_tb = (const float*)d_in[8];
  const float* w1r_tb = (const float*)d_in[9];
  const float* w2l_bt = (const float*)d_in[10];
  const float* w2r_bt = (const float*)d_in[11];
  const float* w2l_tb = (const float*)d_in[12];
  const float* w2r_tb = (const float*)d_in[13];
  const float* b1_bt = (const float*)d_in[14];
  const float* b1_tb = (const float*)d_in[15];
  const float* b2_bt = (const float*)d_in[16];
  const float* b2_tb = (const float*)d_in[17];

  const int NS_ = in_sizes[0];
  const int NT_ = in_sizes[1];
  const int nE = in_sizes[2] / 2;
  const int nL = in_sizes[3] / 2;
  float* out = (float*)d_out;

  if (NS_ > 65535 || NT_ > 65535) return;  // packing assumption

  const int nbT = (NT_ + 63) >> 6;
  const int nbS = (NS_ + 63) >> 6;
  if (nbT > 800 || nbS > 800 || nbT + nbS > 1600) return;

  char* ws = (char*)d_ws;
  size_t o = 0;
  auto alloc = [&](size_t bytes) -> void* {
    void* p = ws + o;
    o = (o + bytes + 255) & ~(size_t)255;
    return p;
  };
  int* boffT = (int*)alloc(((size_t)nbT + 1) * 4);
  int* bcurT = (int*)alloc((size_t)nbT * 4);
  int* boffS = (int*)alloc(((size_t)nbS + 1) * 4);
  int* bcurS = (int*)alloc((size_t)nbS * 4);
  unsigned* ebufT = (unsigned*)alloc((size_t)nE * 4);
  unsigned* ebufS = (unsigned*)alloc((size_t)nE * 4);
  int* noffT = (int*)alloc(((size_t)NT_ + 1) * 4);
  int* noffS = (int*)alloc(((size_t)NS_ + 1) * 4);
  int* adjT = (int*)alloc((size_t)nE * 4);
  int* adjS = (int*)alloc((size_t)nE * 4);
  float* wT1 = (float*)alloc(256 * HD * 4);
  float* wT2 = (float*)alloc(256 * HD * 4);
  float* wT3 = (float*)alloc(256 * HD * 4);
  float* wT4 = (float*)alloc(256 * HD * 4);
  int nmax = imax(NS_, NT_);
  float* agg = (float*)alloc((size_t)nmax * HD * 4);
  float* h1s = (float*)alloc((size_t)NS_ * HD * 4);
  float* h1t = (float*)alloc((size_t)NT_ * HD * 4);
  float* h3s = (float*)alloc((size_t)NS_ * HD * 4);
  float* h3t = (float*)alloc((size_t)NT_ * HD * 4);
  if (o > ws_size) return;

  // ---- bucket sort -> per-node CSR (both directions) ----
  hipMemsetAsync(bcurT, 0, (size_t)nbT * 4, stream);
  hipMemsetAsync(bcurS, 0, (size_t)nbS * 4, stream);
  k_bhist<<<64, 256, 0, stream>>>(ei, nE, bcurT, nbT, bcurS, nbS);
  k_bscan<<<2, 1024, 0, stream>>>(bcurT, boffT, nbT, bcurS, boffS, nbS);
  k_bscatter<<<ceil_div(nE, SC_CH), 256, 0, stream>>>(ei, nE, bcurT, nbT, ebufT,
                                                      bcurS, nbS, ebufS);
  k_bsort<<<nbT, 256, 0, stream>>>(ebufT, boffT, noffT, adjT, NT_, nE);
  k_bsort<<<nbS, 256, 0, stream>>>(ebufS, boffS, noffS, adjS, NS_, nE);

  // ---- weight prep ----
  int wgrid = ceil_div(256 * HD, 256);
  k_build_wT<<<wgrid, 256, 0, stream>>>(w1l_bt, w1r_bt, wT1);
  k_build_wT<<<wgrid, 256, 0, stream>>>(w1l_tb, w1r_tb, wT2);
  k_build_wT<<<wgrid, 256, 0, stream>>>(w2l_bt, w2r_bt, wT3);
  k_build_wT<<<wgrid, 256, 0, stream>>>(w2l_tb, w2r_tb, wT4);

  // ---- layer 1 ----
  k_agg_mean<<<ceil_div(NT_, 4), 256, 0, stream>>>(semb, snid, noffT, adjT, agg, NT_);
  k_gemm_fused<<<ceil_div(NT_, 32), 256, 0, stream>>>(agg, temb, tnid, wT1, b1_bt, nullptr,
                                                      h1t, NT_, 1);
  k_agg_mean<<<ceil_div(NS_, 4), 256, 0, stream>>>(temb, tnid, noffS, adjS, agg, NS_);
  k_gemm_fused<<<ceil_div(NS_, 32), 256, 0, stream>>>(agg, semb, snid, wT2, b1_tb, nullptr,
                                                      h1s, NS_, 1);

  // ---- layer 2 ----
  k_agg_mean<<<ceil_div(NT_, 4), 256, 0, stream>>>(h1s, nullptr, noffT, adjT, agg, NT_);
  k_gemm_fused<<<ceil_div(NT_, 32), 256, 0, stream>>>(agg, h1t, nullptr, wT3, b2_bt, h1t,
                                                      h3t, NT_, 0);
  k_agg_mean<<<ceil_div(NS_, 4), 256, 0, stream>>>(h1t, nullptr, noffS, adjS, agg, NS_);
  k_gemm_fused<<<ceil_div(NS_, 32), 256, 0, stream>>>(agg, h1s, nullptr, wT4, b2_tb, h1s,
                                                      h3s, NS_, 0);

  // ---- classifier ----
  k_classifier<<<ceil_div(nL, 4), 256, 0, stream>>>(eli, nL, h3s, h3t, out);
}

// Round 4
// 426.440 us; speedup vs baseline: 5.6689x; 1.3566x over previous
//
#include <hip/hip_runtime.h>
#include <cstdint>
#include <cstddef>

#define HD 128  // hidden channels

typedef __attribute__((ext_vector_type(8))) short bf16x8;
typedef __attribute__((ext_vector_type(4))) float f32x4;

static inline int ceil_div(int a, int b) { return (a + b - 1) / b; }
static inline int imax(int a, int b) { return a > b ? a : b; }

// f32 -> bf16 (RNE) as raw bits
__device__ __forceinline__ unsigned short f2bf(float f) {
  unsigned u = __float_as_uint(f);
  return (unsigned short)((u + 0x7FFFu + ((u >> 16) & 1u)) >> 16);
}
__device__ __forceinline__ float bf2f(unsigned short h) {
  return __uint_as_float(((unsigned)h) << 16);
}

// ============ bucket sort of edges (64 dst-nodes per bucket) ============
__global__ __launch_bounds__(256) void k_bhist(const int* __restrict__ ei, int nE,
                                               int* __restrict__ histT, int nbT,
                                               int* __restrict__ histS, int nbS) {
  __shared__ int h[1600];
  int nb = nbT + nbS;
  for (int i = threadIdx.x; i < nb; i += 256) h[i] = 0;
  __syncthreads();
  int stride = gridDim.x * 256;
  for (int e = blockIdx.x * 256 + threadIdx.x; e < nE; e += stride) {
    int s = ei[e];
    int t = ei[nE + e];
    atomicAdd(&h[t >> 6], 1);
    atomicAdd(&h[nbT + (s >> 6)], 1);
  }
  __syncthreads();
  for (int i = threadIdx.x; i < nb; i += 256) {
    int v = h[i];
    if (v) {
      if (i < nbT) atomicAdd(&histT[i], v);
      else atomicAdd(&histS[i - nbT], v);
    }
  }
}

__global__ __launch_bounds__(1024) void k_bscan(int* __restrict__ histA, int* __restrict__ offA, int nA,
                                                int* __restrict__ histB, int* __restrict__ offB, int nB) {
  int* hist = blockIdx.x ? histB : histA;
  int* off = blockIdx.x ? offB : offA;
  int n = blockIdx.x ? nB : nA;
  __shared__ int wsum[16];
  int tid = threadIdx.x;
  int lane = tid & 63;
  int wid = tid >> 6;
  int v = (tid < n) ? hist[tid] : 0;
  int x = v;
#pragma unroll
  for (int d = 1; d < 64; d <<= 1) {
    int y = __shfl_up(x, d, 64);
    if (lane >= d) x += y;
  }
  if (lane == 63) wsum[wid] = x;
  __syncthreads();
  if (wid == 0) {
    int s = (lane < 16) ? wsum[lane] : 0;
#pragma unroll
    for (int d = 1; d < 16; d <<= 1) {
      int y = __shfl_up(s, d, 64);
      if (lane >= d) s += y;
    }
    if (lane < 16) wsum[lane] = s;
  }
  __syncthreads();
  int wofs = (wid > 0) ? wsum[wid - 1] : 0;
  int exc = wofs + x - v;
  if (tid < n) {
    off[tid] = exc;
    hist[tid] = exc;  // cursor
  }
  if (tid == 0) off[n] = wsum[15];
}

#define SC_CH 2048
__global__ __launch_bounds__(256) void k_bscatter(const int* __restrict__ ei, int nE,
                                                  int* __restrict__ curT, int nbT,
                                                  unsigned* __restrict__ ebufT,
                                                  int* __restrict__ curS, int nbS,
                                                  unsigned* __restrict__ ebufS) {
  __shared__ unsigned epk[SC_CH];
  __shared__ int cntT[800], baseT[800], cntS[800], baseS[800];
  int tid = threadIdx.x;
  int e0 = blockIdx.x * SC_CH;
  for (int i = tid; i < nbT; i += 256) cntT[i] = 0;
  for (int i = tid; i < nbS; i += 256) cntS[i] = 0;
  for (int i = tid; i < SC_CH; i += 256) {
    int e = e0 + i;
    epk[i] = (e < nE) ? (((unsigned)ei[e] << 16) | (unsigned)ei[nE + e]) : 0xFFFFFFFFu;
  }
  __syncthreads();
  int rT[8], rS[8];
#pragma unroll
  for (int j = 0; j < 8; ++j) {
    int i = tid * 8 + j;
    unsigned p = epk[i];
    if (p != 0xFFFFFFFFu) {
      int t = (int)(p & 0xFFFFu);
      int s = (int)(p >> 16);
      rT[j] = atomicAdd(&cntT[t >> 6], 1);
      rS[j] = atomicAdd(&cntS[s >> 6], 1);
    }
  }
  __syncthreads();
  for (int b = tid; b < nbT; b += 256) baseT[b] = cntT[b] ? atomicAdd(&curT[b], cntT[b]) : 0;
  for (int b = tid; b < nbS; b += 256) baseS[b] = cntS[b] ? atomicAdd(&curS[b], cntS[b]) : 0;
  __syncthreads();
#pragma unroll
  for (int j = 0; j < 8; ++j) {
    int i = tid * 8 + j;
    unsigned p = epk[i];
    if (p != 0xFFFFFFFFu) {
      unsigned t = p & 0xFFFFu;
      unsigned s = p >> 16;
      ebufT[baseT[t >> 6] + rT[j]] = (s << 6) | (t & 63u);
      ebufS[baseS[s >> 6] + rS[j]] = (t << 6) | (s & 63u);
    }
  }
}

// ============ per-bucket counting sort -> per-node CSR ============
__global__ __launch_bounds__(256) void k_bsort(const unsigned* __restrict__ ebuf,
                                               const int* __restrict__ boff,
                                               int* __restrict__ noff,
                                               int* __restrict__ adj,
                                               int ndst, int nE) {
  __shared__ int cnt[64];
  __shared__ int pos[64];
  int b = blockIdx.x;
  int tid = threadIdx.x;
  if (tid < 64) cnt[tid] = 0;
  __syncthreads();
  int beg = boff[b], end = boff[b + 1];
  for (int k = beg + tid; k < end; k += 256) {
    atomicAdd(&cnt[ebuf[k] & 63u], 1);
  }
  __syncthreads();
  if (tid < 64) {
    int v = cnt[tid];
    int x = v;
#pragma unroll
    for (int d = 1; d < 64; d <<= 1) {
      int y = __shfl_up(x, d, 64);
      if (tid >= d) x += y;
    }
    int start = beg + x - v;
    pos[tid] = start;
    int node = (b << 6) + tid;
    if (node < ndst) noff[node] = start;
  }
  __syncthreads();
  for (int k = beg + tid; k < end; k += 256) {
    unsigned e = ebuf[k];
    int p = atomicAdd(&pos[e & 63u], 1);
    adj[p] = (int)(e >> 6);
  }
  if (b == 0 && tid == 0) noff[ndst] = nE;
}

// ============ scatter-mean (gather form over per-node CSR) ============
__global__ __launch_bounds__(256) void k_agg_mean(
    const float* __restrict__ xsrc, const int* __restrict__ smap,
    const int* __restrict__ noff, const int* __restrict__ adj,
    float* __restrict__ agg, int ndst) {
  int gw = (int)((blockIdx.x * 256 + threadIdx.x) >> 6);
  int lane = threadIdx.x & 63;
  if (gw >= ndst) return;
  int beg = noff[gw], end = noff[gw + 1];
  float ax = 0.f, ay = 0.f;
  int k = beg;
  for (; k + 1 < end; k += 2) {
    int n0 = adj[k];
    int n1 = adj[k + 1];
    if (smap) {
      n0 = smap[n0];
      n1 = smap[n1];
    }
    float2 v0 = ((const float2*)xsrc)[(size_t)n0 * 64 + lane];
    float2 v1 = ((const float2*)xsrc)[(size_t)n1 * 64 + lane];
    ax += v0.x + v1.x;
    ay += v0.y + v1.y;
  }
  if (k < end) {
    int n0 = adj[k];
    if (smap) n0 = smap[n0];
    float2 v0 = ((const float2*)xsrc)[(size_t)n0 * 64 + lane];
    ax += v0.x;
    ay += v0.y;
  }
  int deg = end - beg;
  float inv = deg ? 1.0f / (float)deg : 0.0f;
  ((float2*)agg)[(size_t)gw * 64 + lane] = make_float2(ax * inv, ay * inv);
}

// ============ weight prep: fragment-ordered bf16 hi/lo planes ============
// B[k][j] = wl[j][k] (k<128) | wr[j][k-128]. Fragment order for 16x16x32 MFMA:
// element (ks, cf, lane, j): k = ks*32 + (lane>>4)*8 + j, col = cf*16 + (lane&15)
// flat idx = (((ks*8)+cf)*64 + lane)*8 + j   (16 ks x 8 cf x 64 lanes x 8)
__global__ void k_build_pack(const float* __restrict__ wl, const float* __restrict__ wr,
                             short* __restrict__ Bh, short* __restrict__ Bl) {
  int idx = blockIdx.x * blockDim.x + threadIdx.x;
  if (idx >= 256 * HD) return;
  int j = idx & 7;
  int lane = (idx >> 3) & 63;
  int cf = (idx >> 9) & 7;
  int ks = idx >> 12;
  int k = ks * 32 + (lane >> 4) * 8 + j;
  int col = cf * 16 + (lane & 15);
  float val = (k < HD) ? wl[col * HD + k] : wr[col * HD + (k - HD)];
  unsigned short hi = f2bf(val);
  unsigned short lo = f2bf(val - bf2f(hi));
  Bh[idx] = (short)hi;
  Bl[idx] = (short)lo;
}

// ============ MFMA GEMM (split-bf16 x3) + bias + L2-norm + leaky/resid ============
// A_cat[row] = agg[row][0..127] ++ x[row][0..127]; out = norm(A_cat @ B + bias)
// block 256 = 4 waves; wave handles 32 rows x 128 cols; no LDS.
__global__ __launch_bounds__(256) void k_gemm_mfma(
    const float* __restrict__ agg,
    const float* __restrict__ xdst,
    const int* __restrict__ xidx,
    const short* __restrict__ Bh, const short* __restrict__ Bl,
    const float* __restrict__ bias,
    const float* __restrict__ resid,
    float* __restrict__ out, int n, int leaky) {
  int t = threadIdx.x;
  int lane = t & 63;
  int wv = t >> 6;
  int l15 = lane & 15;
  int kg = lane >> 4;  // 0..3
  int baseRow = blockIdx.x * 128 + wv * 32;

  f32x4 acc[2][8];
  float bc = bias ? 0.f : 0.f;
  (void)bc;
#pragma unroll
  for (int cf = 0; cf < 8; ++cf) {
    float b = bias[cf * 16 + l15];
    acc[0][cf] = (f32x4){b, b, b, b};
    acc[1][cf] = (f32x4){b, b, b, b};
  }

  int row0 = baseRow + l15;
  int row1 = row0 + 16;
  int r0c = (row0 < n) ? row0 : (n - 1);
  int r1c = (row1 < n) ? row1 : (n - 1);
  int x0 = xidx ? xidx[r0c] : r0c;
  int x1 = xidx ? xidx[r1c] : r1c;
  const float* a0p = agg + (size_t)r0c * HD;
  const float* a1p = agg + (size_t)r1c * HD;
  const float* x0p = xdst + (size_t)x0 * HD;
  const float* x1p = xdst + (size_t)x1 * HD;

  for (int ks = 0; ks < 8; ++ks) {
    // A: 8 fp32 per row-frag at column ks*32 + kg*8 (chunks never straddle 128)
    const float* s0 = (ks < 4) ? (a0p + ks * 32 + kg * 8) : (x0p + (ks - 4) * 32 + kg * 8);
    const float* s1 = (ks < 4) ? (a1p + ks * 32 + kg * 8) : (x1p + (ks - 4) * 32 + kg * 8);
    f32x4 u0 = ((const f32x4*)s0)[0];
    f32x4 v0 = ((const f32x4*)s0)[1];
    f32x4 u1 = ((const f32x4*)s1)[0];
    f32x4 v1 = ((const f32x4*)s1)[1];
    bf16x8 ah0, al0, ah1, al1;
#pragma unroll
    for (int j = 0; j < 4; ++j) {
      unsigned short h;
      h = f2bf(u0[j]); ah0[j] = (short)h; al0[j] = (short)f2bf(u0[j] - bf2f(h));
      h = f2bf(v0[j]); ah0[j + 4] = (short)h; al0[j + 4] = (short)f2bf(v0[j] - bf2f(h));
      h = f2bf(u1[j]); ah1[j] = (short)h; al1[j] = (short)f2bf(u1[j] - bf2f(h));
      h = f2bf(v1[j]); ah1[j + 4] = (short)h; al1[j + 4] = (short)f2bf(v1[j] - bf2f(h));
    }
    const bf16x8* bhp = (const bf16x8*)Bh + (size_t)(ks * 8) * 64 + lane;
    const bf16x8* blp = (const bf16x8*)Bl + (size_t)(ks * 8) * 64 + lane;
#pragma unroll
    for (int cf = 0; cf < 8; ++cf) {
      bf16x8 bh = bhp[cf * 64];
      bf16x8 bl = blp[cf * 64];
      acc[0][cf] = __builtin_amdgcn_mfma_f32_16x16x32_bf16(ah0, bh, acc[0][cf], 0, 0, 0);
      acc[0][cf] = __builtin_amdgcn_mfma_f32_16x16x32_bf16(ah0, bl, acc[0][cf], 0, 0, 0);
      acc[0][cf] = __builtin_amdgcn_mfma_f32_16x16x32_bf16(al0, bh, acc[0][cf], 0, 0, 0);
      acc[1][cf] = __builtin_amdgcn_mfma_f32_16x16x32_bf16(ah1, bh, acc[1][cf], 0, 0, 0);
      acc[1][cf] = __builtin_amdgcn_mfma_f32_16x16x32_bf16(ah1, bl, acc[1][cf], 0, 0, 0);
      acc[1][cf] = __builtin_amdgcn_mfma_f32_16x16x32_bf16(al1, bh, acc[1][cf], 0, 0, 0);
    }
  }

  // epilogue: C layout col = lane&15, row = (lane>>4)*4 + reg (HW-verified)
#pragma unroll
  for (int rf = 0; rf < 2; ++rf) {
    float ss[4] = {0.f, 0.f, 0.f, 0.f};
#pragma unroll
    for (int cf = 0; cf < 8; ++cf) {
#pragma unroll
      for (int rg = 0; rg < 4; ++rg) ss[rg] += acc[rf][cf][rg] * acc[rf][cf][rg];
    }
#pragma unroll
    for (int rg = 0; rg < 4; ++rg) {
#pragma unroll
      for (int m = 1; m < 16; m <<= 1) ss[rg] += __shfl_xor(ss[rg], m, 64);
    }
#pragma unroll
    for (int rg = 0; rg < 4; ++rg) {
      int row = baseRow + rf * 16 + kg * 4 + rg;
      if (row >= n) continue;
      float inv = 1.0f / fmaxf(sqrtf(ss[rg]), 1e-12f);
#pragma unroll
      for (int cf = 0; cf < 8; ++cf) {
        float v = acc[rf][cf][rg] * inv;
        if (leaky) v = (v > 0.f) ? v : 0.01f * v;
        int col = cf * 16 + l15;
        if (resid) v += resid[(size_t)row * HD + col];
        out[(size_t)row * HD + col] = v;
      }
    }
  }
}

// ---------------- classifier ----------------
__global__ __launch_bounds__(256) void k_classifier(
    const int* __restrict__ eli, int nL,
    const float* __restrict__ h3s, const float* __restrict__ h3t,
    float* __restrict__ out) {
  int w = (int)((blockIdx.x * 256 + threadIdx.x) >> 6);
  int lane = threadIdx.x & 63;
  if (w >= nL) return;
  int s = eli[w];
  int t = eli[nL + w];
  float2 a = ((const float2*)h3s)[(size_t)s * 64 + lane];
  float2 b = ((const float2*)h3t)[(size_t)t * 64 + lane];
  float p = a.x * b.x + a.y * b.y;
#pragma unroll
  for (int ofs = 32; ofs > 0; ofs >>= 1) p += __shfl_xor(p, ofs, 64);
  if (lane == 0) out[w] = p;
}

extern "C" void kernel_launch(void* const* d_in, const int* in_sizes, int n_in,
                              void* d_out, int out_size, void* d_ws, size_t ws_size,
                              hipStream_t stream) {
  (void)n_in;
  (void)out_size;
  const int* snid = (const int*)d_in[0];
  const int* tnid = (const int*)d_in[1];
  const int* ei = (const int*)d_in[2];
  const int* eli = (const int*)d_in[3];
  const float* semb = (const float*)d_in[4];
  const float* temb = (const float*)d_in[5];
  const float* w1l_bt = (const float*)d_in[6];
  const float* w1r_bt = (const float*)d_in[7];
  const float* w1l_tb = (const float*)d_in[8];
  const float* w1r_tb = (const float*)d_in[9];
  const float* w2l_bt = (const float*)d_in[10];
  const float* w2r_bt = (const float*)d_in[11];
  const float* w2l_tb = (const float*)d_in[12];
  const float* w2r_tb = (const float*)d_in[13];
  const float* b1_bt = (const float*)d_in[14];
  const float* b1_tb = (const float*)d_in[15];
  const float* b2_bt = (const float*)d_in[16];
  const float* b2_tb = (const float*)d_in[17];

  const int NS_ = in_sizes[0];
  const int NT_ = in_sizes[1];
  const int nE = in_sizes[2] / 2;
  const int nL = in_sizes[3] / 2;
  float* out = (float*)d_out;

  if (NS_ > 65535 || NT_ > 65535) return;  // packing assumption

  const int nbT = (NT_ + 63) >> 6;
  const int nbS = (NS_ + 63) >> 6;
  if (nbT > 800 || nbS > 800 || nbT + nbS > 1600) return;

  char* ws = (char*)d_ws;
  size_t o = 0;
  auto alloc = [&](size_t bytes) -> void* {
    void* p = ws + o;
    o = (o + bytes + 255) & ~(size_t)255;
    return p;
  };
  int* boffT = (int*)alloc(((size_t)nbT + 1) * 4);
  int* bcurT = (int*)alloc((size_t)nbT * 4);
  int* boffS = (int*)alloc(((size_t)nbS + 1) * 4);
  int* bcurS = (int*)alloc((size_t)nbS * 4);
  unsigned* ebufT = (unsigned*)alloc((size_t)nE * 4);
  unsigned* ebufS = (unsigned*)alloc((size_t)nE * 4);
  int* noffT = (int*)alloc(((size_t)NT_ + 1) * 4);
  int* noffS = (int*)alloc(((size_t)NS_ + 1) * 4);
  int* adjT = (int*)alloc((size_t)nE * 4);
  int* adjS = (int*)alloc((size_t)nE * 4);
  short* Bh1 = (short*)alloc(256 * HD * 2);
  short* Bl1 = (short*)alloc(256 * HD * 2);
  short* Bh2 = (short*)alloc(256 * HD * 2);
  short* Bl2 = (short*)alloc(256 * HD * 2);
  short* Bh3 = (short*)alloc(256 * HD * 2);
  short* Bl3 = (short*)alloc(256 * HD * 2);
  short* Bh4 = (short*)alloc(256 * HD * 2);
  short* Bl4 = (short*)alloc(256 * HD * 2);
  int nmax = imax(NS_, NT_);
  float* agg = (float*)alloc((size_t)nmax * HD * 4);
  float* h1s = (float*)alloc((size_t)NS_ * HD * 4);
  float* h1t = (float*)alloc((size_t)NT_ * HD * 4);
  float* h3s = (float*)alloc((size_t)NS_ * HD * 4);
  float* h3t = (float*)alloc((size_t)NT_ * HD * 4);
  if (o > ws_size) return;

  // ---- bucket sort -> per-node CSR (both directions) ----
  hipMemsetAsync(bcurT, 0, (size_t)nbT * 4, stream);
  hipMemsetAsync(bcurS, 0, (size_t)nbS * 4, stream);
  k_bhist<<<64, 256, 0, stream>>>(ei, nE, bcurT, nbT, bcurS, nbS);
  k_bscan<<<2, 1024, 0, stream>>>(bcurT, boffT, nbT, bcurS, boffS, nbS);
  k_bscatter<<<ceil_div(nE, SC_CH), 256, 0, stream>>>(ei, nE, bcurT, nbT, ebufT,
                                                      bcurS, nbS, ebufS);
  k_bsort<<<nbT, 256, 0, stream>>>(ebufT, boffT, noffT, adjT, NT_, nE);
  k_bsort<<<nbS, 256, 0, stream>>>(ebufS, boffS, noffS, adjS, NS_, nE);

  // ---- weight prep (fragment-ordered bf16 hi/lo) ----
  int wgrid = ceil_div(256 * HD, 256);
  k_build_pack<<<wgrid, 256, 0, stream>>>(w1l_bt, w1r_bt, Bh1, Bl1);
  k_build_pack<<<wgrid, 256, 0, stream>>>(w1l_tb, w1r_tb, Bh2, Bl2);
  k_build_pack<<<wgrid, 256, 0, stream>>>(w2l_bt, w2r_bt, Bh3, Bl3);
  k_build_pack<<<wgrid, 256, 0, stream>>>(w2l_tb, w2r_tb, Bh4, Bl4);

  // ---- layer 1 ----
  k_agg_mean<<<ceil_div(NT_, 4), 256, 0, stream>>>(semb, snid, noffT, adjT, agg, NT_);
  k_gemm_mfma<<<ceil_div(NT_, 128), 256, 0, stream>>>(agg, temb, tnid, Bh1, Bl1, b1_bt,
                                                      nullptr, h1t, NT_, 1);
  k_agg_mean<<<ceil_div(NS_, 4), 256, 0, stream>>>(temb, tnid, noffS, adjS, agg, NS_);
  k_gemm_mfma<<<ceil_div(NS_, 128), 256, 0, stream>>>(agg, semb, snid, Bh2, Bl2, b1_tb,
                                                      nullptr, h1s, NS_, 1);

  // ---- layer 2 ----
  k_agg_mean<<<ceil_div(NT_, 4), 256, 0, stream>>>(h1s, nullptr, noffT, adjT, agg, NT_);
  k_gemm_mfma<<<ceil_div(NT_, 128), 256, 0, stream>>>(agg, h1t, nullptr, Bh3, Bl3, b2_bt,
                                                      h1t, h3t, NT_, 0);
  k_agg_mean<<<ceil_div(NS_, 4), 256, 0, stream>>>(h1t, nullptr, noffS, adjS, agg, NS_);
  k_gemm_mfma<<<ceil_div(NS_, 128), 256, 0, stream>>>(agg, h1s, nullptr, Bh4, Bl4, b2_tb,
                                                      h1s, h3s, NS_, 0);

  // ---- classifier ----
  k_classifier<<<ceil_div(nL, 4), 256, 0, stream>>>(eli, nL, h3s, h3t, out);
}

// Round 5
// 385.830 us; speedup vs baseline: 6.2655x; 1.1053x over previous
//
#include <hip/hip_runtime.h>
#include <cstdint>
#include <cstddef>

#define HD 128  // hidden channels

typedef __attribute__((ext_vector_type(8))) short bf16x8;
typedef __attribute__((ext_vector_type(4))) float f32x4;

static inline int ceil_div(int a, int b) { return (a + b - 1) / b; }
static inline int imax(int a, int b) { return a > b ? a : b; }

// f32 -> bf16 (RNE) as raw bits
__device__ __forceinline__ unsigned short f2bf(float f) {
  unsigned u = __float_as_uint(f);
  return (unsigned short)((u + 0x7FFFu + ((u >> 16) & 1u)) >> 16);
}
__device__ __forceinline__ float bf2f(unsigned short h) {
  return __uint_as_float(((unsigned)h) << 16);
}

// ============ bucket sort of edges (64 dst-nodes per bucket) ============
__global__ __launch_bounds__(256) void k_bhist(const int* __restrict__ ei, int nE,
                                               int* __restrict__ histT, int nbT,
                                               int* __restrict__ histS, int nbS) {
  __shared__ int h[1600];
  int nb = nbT + nbS;
  for (int i = threadIdx.x; i < nb; i += 256) h[i] = 0;
  __syncthreads();
  int stride = gridDim.x * 256;
  for (int e = blockIdx.x * 256 + threadIdx.x; e < nE; e += stride) {
    int s = ei[e];
    int t = ei[nE + e];
    atomicAdd(&h[t >> 6], 1);
    atomicAdd(&h[nbT + (s >> 6)], 1);
  }
  __syncthreads();
  for (int i = threadIdx.x; i < nb; i += 256) {
    int v = h[i];
    if (v) {
      if (i < nbT) atomicAdd(&histT[i], v);
      else atomicAdd(&histS[i - nbT], v);
    }
  }
}

__global__ __launch_bounds__(1024) void k_bscan(int* __restrict__ histA, int* __restrict__ offA, int nA,
                                                int* __restrict__ histB, int* __restrict__ offB, int nB) {
  int* hist = blockIdx.x ? histB : histA;
  int* off = blockIdx.x ? offB : offA;
  int n = blockIdx.x ? nB : nA;
  __shared__ int wsum[16];
  int tid = threadIdx.x;
  int lane = tid & 63;
  int wid = tid >> 6;
  int v = (tid < n) ? hist[tid] : 0;
  int x = v;
#pragma unroll
  for (int d = 1; d < 64; d <<= 1) {
    int y = __shfl_up(x, d, 64);
    if (lane >= d) x += y;
  }
  if (lane == 63) wsum[wid] = x;
  __syncthreads();
  if (wid == 0) {
    int s = (lane < 16) ? wsum[lane] : 0;
#pragma unroll
    for (int d = 1; d < 16; d <<= 1) {
      int y = __shfl_up(s, d, 64);
      if (lane >= d) s += y;
    }
    if (lane < 16) wsum[lane] = s;
  }
  __syncthreads();
  int wofs = (wid > 0) ? wsum[wid - 1] : 0;
  int exc = wofs + x - v;
  if (tid < n) {
    off[tid] = exc;
    hist[tid] = exc;  // cursor
  }
  if (tid == 0) off[n] = wsum[15];
}

#define SC_CH 2048
__global__ __launch_bounds__(256) void k_bscatter(const int* __restrict__ ei, int nE,
                                                  int* __restrict__ curT, int nbT,
                                                  unsigned* __restrict__ ebufT,
                                                  int* __restrict__ curS, int nbS,
                                                  unsigned* __restrict__ ebufS) {
  __shared__ unsigned epk[SC_CH];
  __shared__ int cntT[800], baseT[800], cntS[800], baseS[800];
  int tid = threadIdx.x;
  int e0 = blockIdx.x * SC_CH;
  for (int i = tid; i < nbT; i += 256) cntT[i] = 0;
  for (int i = tid; i < nbS; i += 256) cntS[i] = 0;
  for (int i = tid; i < SC_CH; i += 256) {
    int e = e0 + i;
    epk[i] = (e < nE) ? (((unsigned)ei[e] << 16) | (unsigned)ei[nE + e]) : 0xFFFFFFFFu;
  }
  __syncthreads();
  int rT[8], rS[8];
#pragma unroll
  for (int j = 0; j < 8; ++j) {
    int i = tid * 8 + j;
    unsigned p = epk[i];
    if (p != 0xFFFFFFFFu) {
      int t = (int)(p & 0xFFFFu);
      int s = (int)(p >> 16);
      rT[j] = atomicAdd(&cntT[t >> 6], 1);
      rS[j] = atomicAdd(&cntS[s >> 6], 1);
    }
  }
  __syncthreads();
  for (int b = tid; b < nbT; b += 256) baseT[b] = cntT[b] ? atomicAdd(&curT[b], cntT[b]) : 0;
  for (int b = tid; b < nbS; b += 256) baseS[b] = cntS[b] ? atomicAdd(&curS[b], cntS[b]) : 0;
  __syncthreads();
#pragma unroll
  for (int j = 0; j < 8; ++j) {
    int i = tid * 8 + j;
    unsigned p = epk[i];
    if (p != 0xFFFFFFFFu) {
      unsigned t = p & 0xFFFFu;
      unsigned s = p >> 16;
      ebufT[baseT[t >> 6] + rT[j]] = (s << 6) | (t & 63u);
      ebufS[baseS[s >> 6] + rS[j]] = (t << 6) | (s & 63u);
    }
  }
}

// ============ per-bucket counting sort -> per-node CSR ============
__global__ __launch_bounds__(256) void k_bsort(const unsigned* __restrict__ ebuf,
                                               const int* __restrict__ boff,
                                               int* __restrict__ noff,
                                               int* __restrict__ adj,
                                               int ndst, int nE) {
  __shared__ int cnt[64];
  __shared__ int pos[64];
  int b = blockIdx.x;
  int tid = threadIdx.x;
  if (tid < 64) cnt[tid] = 0;
  __syncthreads();
  int beg = boff[b], end = boff[b + 1];
  for (int k = beg + tid; k < end; k += 256) {
    atomicAdd(&cnt[ebuf[k] & 63u], 1);
  }
  __syncthreads();
  if (tid < 64) {
    int v = cnt[tid];
    int x = v;
#pragma unroll
    for (int d = 1; d < 64; d <<= 1) {
      int y = __shfl_up(x, d, 64);
      if (tid >= d) x += y;
    }
    int start = beg + x - v;
    pos[tid] = start;
    int node = (b << 6) + tid;
    if (node < ndst) noff[node] = start;
  }
  __syncthreads();
  for (int k = beg + tid; k < end; k += 256) {
    unsigned e = ebuf[k];
    int p = atomicAdd(&pos[e & 63u], 1);
    adj[p] = (int)(e >> 6);
  }
  if (b == 0 && tid == 0) noff[ndst] = nE;
}

// ============ scatter-mean: gather form, 8-deep unroll for MLP ============
__device__ __forceinline__ void agg_one(const float* __restrict__ xsrc,
                                        const int* __restrict__ smap,
                                        const int* __restrict__ noff,
                                        const int* __restrict__ adj,
                                        float* __restrict__ agg, int gw, int lane) {
  int beg = noff[gw], end = noff[gw + 1];
  float ax = 0.f, ay = 0.f;
  int k = beg;
  for (; k + 8 <= end; k += 8) {
    int n[8];
#pragma unroll
    for (int j = 0; j < 8; ++j) n[j] = adj[k + j];
    if (smap) {
#pragma unroll
      for (int j = 0; j < 8; ++j) n[j] = smap[n[j]];
    }
    float2 v[8];
#pragma unroll
    for (int j = 0; j < 8; ++j) v[j] = ((const float2*)xsrc)[(size_t)n[j] * 64 + lane];
#pragma unroll
    for (int j = 0; j < 8; ++j) {
      ax += v[j].x;
      ay += v[j].y;
    }
  }
  for (; k + 2 <= end; k += 2) {
    int n0 = adj[k], n1 = adj[k + 1];
    if (smap) {
      n0 = smap[n0];
      n1 = smap[n1];
    }
    float2 v0 = ((const float2*)xsrc)[(size_t)n0 * 64 + lane];
    float2 v1 = ((const float2*)xsrc)[(size_t)n1 * 64 + lane];
    ax += v0.x + v1.x;
    ay += v0.y + v1.y;
  }
  if (k < end) {
    int n0 = adj[k];
    if (smap) n0 = smap[n0];
    float2 v0 = ((const float2*)xsrc)[(size_t)n0 * 64 + lane];
    ax += v0.x;
    ay += v0.y;
  }
  int deg = end - beg;
  float inv = deg ? 1.0f / (float)deg : 0.0f;
  ((float2*)agg)[(size_t)gw * 64 + lane] = make_float2(ax * inv, ay * inv);
}

// both directions of one layer in a single dispatch (independent work)
__global__ __launch_bounds__(256) void k_agg_dual(
    const float* __restrict__ xA, const int* __restrict__ mA,
    const int* __restrict__ noffA, const int* __restrict__ adjA,
    float* __restrict__ aggA, int nA,
    const float* __restrict__ xB, const int* __restrict__ mB,
    const int* __restrict__ noffB, const int* __restrict__ adjB,
    float* __restrict__ aggB, int nB) {
  int gw = (int)((blockIdx.x * 256 + threadIdx.x) >> 6);
  int lane = threadIdx.x & 63;
  if (gw < nA) {
    agg_one(xA, mA, noffA, adjA, aggA, gw, lane);
  } else if (gw < nA + nB) {
    agg_one(xB, mB, noffB, adjB, aggB, gw - nA, lane);
  }
}

// ============ weight prep: fragment-ordered bf16 hi/lo planes ============
__global__ void k_build_pack(const float* __restrict__ wl, const float* __restrict__ wr,
                             short* __restrict__ Bh, short* __restrict__ Bl) {
  int idx = blockIdx.x * blockDim.x + threadIdx.x;
  if (idx >= 256 * HD) return;
  int j = idx & 7;
  int lane = (idx >> 3) & 63;
  int cf = (idx >> 9) & 7;
  int ks = idx >> 12;
  int k = ks * 32 + (lane >> 4) * 8 + j;
  int col = cf * 16 + (lane & 15);
  float val = (k < HD) ? wl[col * HD + k] : wr[col * HD + (k - HD)];
  unsigned short hi = f2bf(val);
  unsigned short lo = f2bf(val - bf2f(hi));
  Bh[idx] = (short)hi;
  Bl[idx] = (short)lo;
}

// ============ MFMA GEMM (split-bf16 x3) + bias + L2-norm + leaky/resid ============
// out == agg (in-place) is safe: a block reads exactly the rows it writes, and
// all reads of those rows complete before the epilogue stores.
__global__ __launch_bounds__(256) void k_gemm_mfma(
    const float* __restrict__ agg,
    const float* __restrict__ xdst,
    const int* __restrict__ xidx,
    const short* __restrict__ Bh, const short* __restrict__ Bl,
    const float* __restrict__ bias,
    const float* __restrict__ resid,
    float* __restrict__ out, int n, int leaky) {
  int t = threadIdx.x;
  int lane = t & 63;
  int wv = t >> 6;
  int l15 = lane & 15;
  int kg = lane >> 4;  // 0..3
  int baseRow = blockIdx.x * 128 + wv * 32;

  f32x4 acc[2][8];
#pragma unroll
  for (int cf = 0; cf < 8; ++cf) {
    float b = bias[cf * 16 + l15];
    acc[0][cf] = (f32x4){b, b, b, b};
    acc[1][cf] = (f32x4){b, b, b, b};
  }

  int row0 = baseRow + l15;
  int row1 = row0 + 16;
  int r0c = (row0 < n) ? row0 : (n - 1);
  int r1c = (row1 < n) ? row1 : (n - 1);
  int x0 = xidx ? xidx[r0c] : r0c;
  int x1 = xidx ? xidx[r1c] : r1c;
  const float* a0p = agg + (size_t)r0c * HD;
  const float* a1p = agg + (size_t)r1c * HD;
  const float* x0p = xdst + (size_t)x0 * HD;
  const float* x1p = xdst + (size_t)x1 * HD;

  for (int ks = 0; ks < 8; ++ks) {
    const float* s0 = (ks < 4) ? (a0p + ks * 32 + kg * 8) : (x0p + (ks - 4) * 32 + kg * 8);
    const float* s1 = (ks < 4) ? (a1p + ks * 32 + kg * 8) : (x1p + (ks - 4) * 32 + kg * 8);
    f32x4 u0 = ((const f32x4*)s0)[0];
    f32x4 v0 = ((const f32x4*)s0)[1];
    f32x4 u1 = ((const f32x4*)s1)[0];
    f32x4 v1 = ((const f32x4*)s1)[1];
    bf16x8 ah0, al0, ah1, al1;
#pragma unroll
    for (int j = 0; j < 4; ++j) {
      unsigned short h;
      h = f2bf(u0[j]); ah0[j] = (short)h; al0[j] = (short)f2bf(u0[j] - bf2f(h));
      h = f2bf(v0[j]); ah0[j + 4] = (short)h; al0[j + 4] = (short)f2bf(v0[j] - bf2f(h));
      h = f2bf(u1[j]); ah1[j] = (short)h; al1[j] = (short)f2bf(u1[j] - bf2f(h));
      h = f2bf(v1[j]); ah1[j + 4] = (short)h; al1[j + 4] = (short)f2bf(v1[j] - bf2f(h));
    }
    const bf16x8* bhp = (const bf16x8*)Bh + (size_t)(ks * 8) * 64 + lane;
    const bf16x8* blp = (const bf16x8*)Bl + (size_t)(ks * 8) * 64 + lane;
#pragma unroll
    for (int cf = 0; cf < 8; ++cf) {
      bf16x8 bh = bhp[cf * 64];
      bf16x8 bl = blp[cf * 64];
      acc[0][cf] = __builtin_amdgcn_mfma_f32_16x16x32_bf16(ah0, bh, acc[0][cf], 0, 0, 0);
      acc[0][cf] = __builtin_amdgcn_mfma_f32_16x16x32_bf16(ah0, bl, acc[0][cf], 0, 0, 0);
      acc[0][cf] = __builtin_amdgcn_mfma_f32_16x16x32_bf16(al0, bh, acc[0][cf], 0, 0, 0);
      acc[1][cf] = __builtin_amdgcn_mfma_f32_16x16x32_bf16(ah1, bh, acc[1][cf], 0, 0, 0);
      acc[1][cf] = __builtin_amdgcn_mfma_f32_16x16x32_bf16(ah1, bl, acc[1][cf], 0, 0, 0);
      acc[1][cf] = __builtin_amdgcn_mfma_f32_16x16x32_bf16(al1, bh, acc[1][cf], 0, 0, 0);
    }
  }

  // epilogue: C layout col = lane&15, row = (lane>>4)*4 + reg
#pragma unroll
  for (int rf = 0; rf < 2; ++rf) {
    float ss[4] = {0.f, 0.f, 0.f, 0.f};
#pragma unroll
    for (int cf = 0; cf < 8; ++cf) {
#pragma unroll
      for (int rg = 0; rg < 4; ++rg) ss[rg] += acc[rf][cf][rg] * acc[rf][cf][rg];
    }
#pragma unroll
    for (int rg = 0; rg < 4; ++rg) {
#pragma unroll
      for (int m = 1; m < 16; m <<= 1) ss[rg] += __shfl_xor(ss[rg], m, 64);
    }
#pragma unroll
    for (int rg = 0; rg < 4; ++rg) {
      int row = baseRow + rf * 16 + kg * 4 + rg;
      if (row >= n) continue;
      float inv = 1.0f / fmaxf(sqrtf(ss[rg]), 1e-12f);
#pragma unroll
      for (int cf = 0; cf < 8; ++cf) {
        float v = acc[rf][cf][rg] * inv;
        if (leaky) v = (v > 0.f) ? v : 0.01f * v;
        int col = cf * 16 + l15;
        if (resid) v += resid[(size_t)row * HD + col];
        out[(size_t)row * HD + col] = v;
      }
    }
  }
}

// ---------------- classifier ----------------
__global__ __launch_bounds__(256) void k_classifier(
    const int* __restrict__ eli, int nL,
    const float* __restrict__ h3s, const float* __restrict__ h3t,
    float* __restrict__ out) {
  int w = (int)((blockIdx.x * 256 + threadIdx.x) >> 6);
  int lane = threadIdx.x & 63;
  if (w >= nL) return;
  int s = eli[w];
  int t = eli[nL + w];
  float2 a = ((const float2*)h3s)[(size_t)s * 64 + lane];
  float2 b = ((const float2*)h3t)[(size_t)t * 64 + lane];
  float p = a.x * b.x + a.y * b.y;
#pragma unroll
  for (int ofs = 32; ofs > 0; ofs >>= 1) p += __shfl_xor(p, ofs, 64);
  if (lane == 0) out[w] = p;
}

extern "C" void kernel_launch(void* const* d_in, const int* in_sizes, int n_in,
                              void* d_out, int out_size, void* d_ws, size_t ws_size,
                              hipStream_t stream) {
  (void)n_in;
  (void)out_size;
  const int* snid = (const int*)d_in[0];
  const int* tnid = (const int*)d_in[1];
  const int* ei = (const int*)d_in[2];
  const int* eli = (const int*)d_in[3];
  const float* semb = (const float*)d_in[4];
  const float* temb = (const float*)d_in[5];
  const float* w1l_bt = (const float*)d_in[6];
  const float* w1r_bt = (const float*)d_in[7];
  const float* w1l_tb = (const float*)d_in[8];
  const float* w1r_tb = (const float*)d_in[9];
  const float* w2l_bt = (const float*)d_in[10];
  const float* w2r_bt = (const float*)d_in[11];
  const float* w2l_tb = (const float*)d_in[12];
  const float* w2r_tb = (const float*)d_in[13];
  const float* b1_bt = (const float*)d_in[14];
  const float* b1_tb = (const float*)d_in[15];
  const float* b2_bt = (const float*)d_in[16];
  const float* b2_tb = (const float*)d_in[17];

  const int NS_ = in_sizes[0];
  const int NT_ = in_sizes[1];
  const int nE = in_sizes[2] / 2;
  const int nL = in_sizes[3] / 2;
  float* out = (float*)d_out;

  if (NS_ > 65535 || NT_ > 65535) return;  // packing assumption

  const int nbT = (NT_ + 63) >> 6;
  const int nbS = (NS_ + 63) >> 6;
  if (nbT > 800 || nbS > 800 || nbT + nbS > 1600) return;

  char* ws = (char*)d_ws;
  size_t o = 0;
  auto alloc = [&](size_t bytes) -> void* {
    void* p = ws + o;
    o = (o + bytes + 255) & ~(size_t)255;
    return p;
  };
  int* boffT = (int*)alloc(((size_t)nbT + 1) * 4);
  int* bcurT = (int*)alloc((size_t)nbT * 4);
  int* boffS = (int*)alloc(((size_t)nbS + 1) * 4);
  int* bcurS = (int*)alloc((size_t)nbS * 4);
  unsigned* ebufT = (unsigned*)alloc((size_t)nE * 4);
  unsigned* ebufS = (unsigned*)alloc((size_t)nE * 4);
  int* noffT = (int*)alloc(((size_t)NT_ + 1) * 4);
  int* noffS = (int*)alloc(((size_t)NS_ + 1) * 4);
  int* adjT = (int*)alloc((size_t)nE * 4);
  int* adjS = (int*)alloc((size_t)nE * 4);
  short* Bh1 = (short*)alloc(256 * HD * 2);
  short* Bl1 = (short*)alloc(256 * HD * 2);
  short* Bh2 = (short*)alloc(256 * HD * 2);
  short* Bl2 = (short*)alloc(256 * HD * 2);
  short* Bh3 = (short*)alloc(256 * HD * 2);
  short* Bl3 = (short*)alloc(256 * HD * 2);
  short* Bh4 = (short*)alloc(256 * HD * 2);
  short* Bl4 = (short*)alloc(256 * HD * 2);
  int nmax = imax(NS_, NT_);
  float* aggA = (float*)alloc((size_t)nmax * HD * 4);  // T-side agg; later h3t
  float* aggB = (float*)alloc((size_t)nmax * HD * 4);  // S-side agg; later h3s
  float* h1s = (float*)alloc((size_t)NS_ * HD * 4);
  float* h1t = (float*)alloc((size_t)NT_ * HD * 4);
  if (o > ws_size) return;

  // ---- bucket sort -> per-node CSR (both directions) ----
  hipMemsetAsync(bcurT, 0, (size_t)nbT * 4, stream);
  hipMemsetAsync(bcurS, 0, (size_t)nbS * 4, stream);
  k_bhist<<<64, 256, 0, stream>>>(ei, nE, bcurT, nbT, bcurS, nbS);
  k_bscan<<<2, 1024, 0, stream>>>(bcurT, boffT, nbT, bcurS, boffS, nbS);
  k_bscatter<<<ceil_div(nE, SC_CH), 256, 0, stream>>>(ei, nE, bcurT, nbT, ebufT,
                                                      bcurS, nbS, ebufS);
  k_bsort<<<nbT, 256, 0, stream>>>(ebufT, boffT, noffT, adjT, NT_, nE);
  k_bsort<<<nbS, 256, 0, stream>>>(ebufS, boffS, noffS, adjS, NS_, nE);

  // ---- weight prep (fragment-ordered bf16 hi/lo) ----
  int wgrid = ceil_div(256 * HD, 256);
  k_build_pack<<<wgrid, 256, 0, stream>>>(w1l_bt, w1r_bt, Bh1, Bl1);
  k_build_pack<<<wgrid, 256, 0, stream>>>(w1l_tb, w1r_tb, Bh2, Bl2);
  k_build_pack<<<wgrid, 256, 0, stream>>>(w2l_bt, w2r_bt, Bh3, Bl3);
  k_build_pack<<<wgrid, 256, 0, stream>>>(w2l_tb, w2r_tb, Bh4, Bl4);

  int aggGrid = ceil_div(NT_ + NS_, 4);

  // ---- layer 1 ----
  k_agg_dual<<<aggGrid, 256, 0, stream>>>(semb, snid, noffT, adjT, aggA, NT_,
                                          temb, tnid, noffS, adjS, aggB, NS_);
  k_gemm_mfma<<<ceil_div(NT_, 128), 256, 0, stream>>>(aggA, temb, tnid, Bh1, Bl1, b1_bt,
                                                      nullptr, h1t, NT_, 1);
  k_gemm_mfma<<<ceil_div(NS_, 128), 256, 0, stream>>>(aggB, semb, snid, Bh2, Bl2, b1_tb,
                                                      nullptr, h1s, NS_, 1);

  // ---- layer 2 (gemm writes in-place over agg; results = h3t, h3s) ----
  k_agg_dual<<<aggGrid, 256, 0, stream>>>(h1s, nullptr, noffT, adjT, aggA, NT_,
                                          h1t, nullptr, noffS, adjS, aggB, NS_);
  k_gemm_mfma<<<ceil_div(NT_, 128), 256, 0, stream>>>(aggA, h1t, nullptr, Bh3, Bl3, b2_bt,
                                                      h1t, aggA, NT_, 0);
  k_gemm_mfma<<<ceil_div(NS_, 128), 256, 0, stream>>>(aggB, h1s, nullptr, Bh4, Bl4, b2_tb,
                                                      h1s, aggB, NS_, 0);

  // ---- classifier ----
  k_classifier<<<ceil_div(nL, 4), 256, 0, stream>>>(eli, nL, aggB, aggA, out);
}

// Round 6
// 337.160 us; speedup vs baseline: 7.1700x; 1.1444x over previous
//
#include <hip/hip_runtime.h>
#include <cstdint>
#include <cstddef>

#define HD 128  // hidden channels

typedef __attribute__((ext_vector_type(8))) short bf16x8;
typedef __attribute__((ext_vector_type(4))) float f32x4;

static inline int ceil_div(int a, int b) { return (a + b - 1) / b; }
static inline int imax(int a, int b) { return a > b ? a : b; }

// f32 -> bf16 (RNE) as raw bits
__device__ __forceinline__ unsigned short f2bf(float f) {
  unsigned u = __float_as_uint(f);
  return (unsigned short)((u + 0x7FFFu + ((u >> 16) & 1u)) >> 16);
}
__device__ __forceinline__ float bf2f(unsigned short h) {
  return __uint_as_float(((unsigned)h) << 16);
}

// ============ bucket sort of edges (64 dst-nodes per bucket) ============
__global__ __launch_bounds__(256) void k_bhist(const int* __restrict__ ei, int nE,
                                               int* __restrict__ histT, int nbT,
                                               int* __restrict__ histS, int nbS) {
  __shared__ int h[1600];
  int nb = nbT + nbS;
  for (int i = threadIdx.x; i < nb; i += 256) h[i] = 0;
  __syncthreads();
  int stride = gridDim.x * 256;
  for (int e = blockIdx.x * 256 + threadIdx.x; e < nE; e += stride) {
    int s = ei[e];
    int t = ei[nE + e];
    atomicAdd(&h[t >> 6], 1);
    atomicAdd(&h[nbT + (s >> 6)], 1);
  }
  __syncthreads();
  for (int i = threadIdx.x; i < nb; i += 256) {
    int v = h[i];
    if (v) {
      if (i < nbT) atomicAdd(&histT[i], v);
      else atomicAdd(&histS[i - nbT], v);
    }
  }
}

__global__ __launch_bounds__(1024) void k_bscan(int* __restrict__ histA, int* __restrict__ offA, int nA,
                                                int* __restrict__ histB, int* __restrict__ offB, int nB) {
  int* hist = blockIdx.x ? histB : histA;
  int* off = blockIdx.x ? offB : offA;
  int n = blockIdx.x ? nB : nA;
  __shared__ int wsum[16];
  int tid = threadIdx.x;
  int lane = tid & 63;
  int wid = tid >> 6;
  int v = (tid < n) ? hist[tid] : 0;
  int x = v;
#pragma unroll
  for (int d = 1; d < 64; d <<= 1) {
    int y = __shfl_up(x, d, 64);
    if (lane >= d) x += y;
  }
  if (lane == 63) wsum[wid] = x;
  __syncthreads();
  if (wid == 0) {
    int s = (lane < 16) ? wsum[lane] : 0;
#pragma unroll
    for (int d = 1; d < 16; d <<= 1) {
      int y = __shfl_up(s, d, 64);
      if (lane >= d) s += y;
    }
    if (lane < 16) wsum[lane] = s;
  }
  __syncthreads();
  int wofs = (wid > 0) ? wsum[wid - 1] : 0;
  int exc = wofs + x - v;
  if (tid < n) {
    off[tid] = exc;
    hist[tid] = exc;  // cursor
  }
  if (tid == 0) off[n] = wsum[15];
}

#define SC_CH 2048
__global__ __launch_bounds__(256) void k_bscatter(const int* __restrict__ ei, int nE,
                                                  int* __restrict__ curT, int nbT,
                                                  unsigned* __restrict__ ebufT,
                                                  int* __restrict__ curS, int nbS,
                                                  unsigned* __restrict__ ebufS) {
  __shared__ unsigned epk[SC_CH];
  __shared__ int cntT[800], baseT[800], cntS[800], baseS[800];
  int tid = threadIdx.x;
  int e0 = blockIdx.x * SC_CH;
  for (int i = tid; i < nbT; i += 256) cntT[i] = 0;
  for (int i = tid; i < nbS; i += 256) cntS[i] = 0;
  for (int i = tid; i < SC_CH; i += 256) {
    int e = e0 + i;
    epk[i] = (e < nE) ? (((unsigned)ei[e] << 16) | (unsigned)ei[nE + e]) : 0xFFFFFFFFu;
  }
  __syncthreads();
  int rT[8], rS[8];
#pragma unroll
  for (int j = 0; j < 8; ++j) {
    int i = tid * 8 + j;
    unsigned p = epk[i];
    if (p != 0xFFFFFFFFu) {
      int t = (int)(p & 0xFFFFu);
      int s = (int)(p >> 16);
      rT[j] = atomicAdd(&cntT[t >> 6], 1);
      rS[j] = atomicAdd(&cntS[s >> 6], 1);
    }
  }
  __syncthreads();
  for (int b = tid; b < nbT; b += 256) baseT[b] = cntT[b] ? atomicAdd(&curT[b], cntT[b]) : 0;
  for (int b = tid; b < nbS; b += 256) baseS[b] = cntS[b] ? atomicAdd(&curS[b], cntS[b]) : 0;
  __syncthreads();
#pragma unroll
  for (int j = 0; j < 8; ++j) {
    int i = tid * 8 + j;
    unsigned p = epk[i];
    if (p != 0xFFFFFFFFu) {
      unsigned t = p & 0xFFFFu;
      unsigned s = p >> 16;
      ebufT[baseT[t >> 6] + rT[j]] = (s << 6) | (t & 63u);
      ebufS[baseS[s >> 6] + rS[j]] = (t << 6) | (s & 63u);
    }
  }
}

// ============ per-bucket counting sort -> per-node CSR ============
__global__ __launch_bounds__(256) void k_bsort(const unsigned* __restrict__ ebuf,
                                               const int* __restrict__ boff,
                                               int* __restrict__ noff,
                                               int* __restrict__ adj,
                                               int ndst, int nE) {
  __shared__ int cnt[64];
  __shared__ int pos[64];
  int b = blockIdx.x;
  int tid = threadIdx.x;
  if (tid < 64) cnt[tid] = 0;
  __syncthreads();
  int beg = boff[b], end = boff[b + 1];
  for (int k = beg + tid; k < end; k += 256) {
    atomicAdd(&cnt[ebuf[k] & 63u], 1);
  }
  __syncthreads();
  if (tid < 64) {
    int v = cnt[tid];
    int x = v;
#pragma unroll
    for (int d = 1; d < 64; d <<= 1) {
      int y = __shfl_up(x, d, 64);
      if (tid >= d) x += y;
    }
    int start = beg + x - v;
    pos[tid] = start;
    int node = (b << 6) + tid;
    if (node < ndst) noff[node] = start;
  }
  __syncthreads();
  for (int k = beg + tid; k < end; k += 256) {
    unsigned e = ebuf[k];
    int p = atomicAdd(&pos[e & 63u], 1);
    adj[p] = (int)(e >> 6);
  }
  if (b == 0 && tid == 0) noff[ndst] = nE;
}

// ============ gather-cast: node-indexed bf16 feature tables ============
// outA[i] = bf16(embA[mapA[i]]), outB likewise; one thread = 4 channels.
__global__ __launch_bounds__(256) void k_cast_gather(
    const float* __restrict__ embA, const int* __restrict__ mapA,
    unsigned short* __restrict__ outA, int nA,
    const float* __restrict__ embB, const int* __restrict__ mapB,
    unsigned short* __restrict__ outB, int nB) {
  int tid = blockIdx.x * 256 + threadIdx.x;
  int row = tid >> 5;
  int q = tid & 31;
  const float* src;
  unsigned short* dst;
  if (row < nA) {
    int r = mapA ? mapA[row] : row;
    src = embA + (size_t)r * HD;
    dst = outA + (size_t)row * HD;
  } else if (row < nA + nB) {
    int rr = row - nA;
    int r = mapB ? mapB[rr] : rr;
    src = embB + (size_t)r * HD;
    dst = outB + (size_t)rr * HD;
  } else {
    return;
  }
  float4 v = ((const float4*)src)[q];
  ushort4 o;
  o.x = f2bf(v.x);
  o.y = f2bf(v.y);
  o.z = f2bf(v.z);
  o.w = f2bf(v.w);
  ((ushort4*)dst)[q] = o;
}

// ============ scatter-mean: bf16 gather, 2 nodes/wave, 8-deep batches ============
__device__ __forceinline__ void resolve_node(
    int g,
    const unsigned short* __restrict__ xA, const int* __restrict__ noffA,
    const int* __restrict__ adjA, float* __restrict__ aggA, int nA,
    const unsigned short* __restrict__ xB, const int* __restrict__ noffB,
    const int* __restrict__ adjB, float* __restrict__ aggB,
    const unsigned short*& x, const int*& adj, float*& agg,
    int& beg, int& end, int& node) {
  if (g < nA) {
    x = xA; adj = adjA; agg = aggA; node = g;
    beg = noffA[g]; end = noffA[g + 1];
  } else {
    int gg = g - nA;
    x = xB; adj = adjB; agg = aggB; node = gg;
    beg = noffB[gg]; end = noffB[gg + 1];
  }
}

__global__ __launch_bounds__(256) void k_agg_dual(
    const unsigned short* __restrict__ xA, const int* __restrict__ noffA,
    const int* __restrict__ adjA, float* __restrict__ aggA, int nA,
    const unsigned short* __restrict__ xB, const int* __restrict__ noffB,
    const int* __restrict__ adjB, float* __restrict__ aggB, int nB) {
  int w = (int)((blockIdx.x * 256 + threadIdx.x) >> 6);
  int lane = threadIdx.x & 63;
  int total = nA + nB;
  int g0 = 2 * w, g1 = 2 * w + 1;
  if (g0 >= total) return;
  const unsigned short *x0, *x1;
  const int *ad0, *ad1;
  float *ag0, *ag1;
  int beg0, end0, node0, beg1, end1, node1;
  resolve_node(g0, xA, noffA, adjA, aggA, nA, xB, noffB, adjB, aggB,
               x0, ad0, ag0, beg0, end0, node0);
  bool has1 = (g1 < total);
  if (has1) {
    resolve_node(g1, xA, noffA, adjA, aggA, nA, xB, noffB, adjB, aggB,
                 x1, ad1, ag1, beg1, end1, node1);
  } else {
    x1 = x0; ad1 = ad0; ag1 = ag0; beg1 = 0; end1 = 0; node1 = 0;
  }
  int d0 = end0 - beg0;
  int d1 = end1 - beg1;
  int safe0 = d0 ? beg0 : 0;
  int safe1 = d1 ? beg1 : 0;
  int dmax = d0 > d1 ? d0 : d1;
  int iters = (dmax + 7) >> 3;
  float a0x = 0.f, a0y = 0.f, a1x = 0.f, a1y = 0.f;
  for (int it = 0; it < iters; ++it) {
    int k0 = beg0 + it * 8;
    int k1 = beg1 + it * 8;
    int i0[8], i1[8];
#pragma unroll
    for (int j = 0; j < 8; ++j) i0[j] = ad0[(k0 + j < end0) ? (k0 + j) : safe0];
#pragma unroll
    for (int j = 0; j < 8; ++j) i1[j] = ad1[(k1 + j < end1) ? (k1 + j) : safe1];
    unsigned v0[8], v1[8];
#pragma unroll
    for (int j = 0; j < 8; ++j)
      v0[j] = ((const unsigned*)(x0 + (size_t)i0[j] * HD))[lane];
#pragma unroll
    for (int j = 0; j < 8; ++j)
      v1[j] = ((const unsigned*)(x1 + (size_t)i1[j] * HD))[lane];
#pragma unroll
    for (int j = 0; j < 8; ++j) {
      float m = (k0 + j < end0) ? 1.f : 0.f;
      a0x = fmaf(m, __uint_as_float(v0[j] << 16), a0x);
      a0y = fmaf(m, __uint_as_float(v0[j] & 0xFFFF0000u), a0y);
    }
#pragma unroll
    for (int j = 0; j < 8; ++j) {
      float m = (k1 + j < end1) ? 1.f : 0.f;
      a1x = fmaf(m, __uint_as_float(v1[j] << 16), a1x);
      a1y = fmaf(m, __uint_as_float(v1[j] & 0xFFFF0000u), a1y);
    }
  }
  float inv0 = d0 ? 1.0f / (float)d0 : 0.0f;
  ((float2*)ag0)[(size_t)node0 * 64 + lane] = make_float2(a0x * inv0, a0y * inv0);
  if (has1) {
    float inv1 = d1 ? 1.0f / (float)d1 : 0.0f;
    ((float2*)ag1)[(size_t)node1 * 64 + lane] = make_float2(a1x * inv1, a1y * inv1);
  }
}

// ============ weight prep: fragment-ordered bf16 hi/lo planes ============
__global__ void k_build_pack(const float* __restrict__ wl, const float* __restrict__ wr,
                             short* __restrict__ Bh, short* __restrict__ Bl) {
  int idx = blockIdx.x * blockDim.x + threadIdx.x;
  if (idx >= 256 * HD) return;
  int j = idx & 7;
  int lane = (idx >> 3) & 63;
  int cf = (idx >> 9) & 7;
  int ks = idx >> 12;
  int k = ks * 32 + (lane >> 4) * 8 + j;
  int col = cf * 16 + (lane & 15);
  float val = (k < HD) ? wl[col * HD + k] : wr[col * HD + (k - HD)];
  unsigned short hi = f2bf(val);
  unsigned short lo = f2bf(val - bf2f(hi));
  Bh[idx] = (short)hi;
  Bl[idx] = (short)lo;
}

// ============ MFMA GEMM (split-bf16 x3) + bias + L2-norm + leaky/resid ============
// out == agg (in-place) is safe: a block reads exactly the rows it writes, and
// all reads of those rows complete before the epilogue stores.
// outB (optional): bf16 copy of the output (for next layer's aggregation).
__global__ __launch_bounds__(256) void k_gemm_mfma(
    const float* __restrict__ agg,
    const float* __restrict__ xdst,
    const int* __restrict__ xidx,
    const short* __restrict__ Bh, const short* __restrict__ Bl,
    const float* __restrict__ bias,
    const float* __restrict__ resid,
    float* __restrict__ out,
    unsigned short* __restrict__ outB,
    int n, int leaky) {
  int t = threadIdx.x;
  int lane = t & 63;
  int wv = t >> 6;
  int l15 = lane & 15;
  int kg = lane >> 4;  // 0..3
  int baseRow = blockIdx.x * 128 + wv * 32;

  f32x4 acc[2][8];
#pragma unroll
  for (int cf = 0; cf < 8; ++cf) {
    float b = bias[cf * 16 + l15];
    acc[0][cf] = (f32x4){b, b, b, b};
    acc[1][cf] = (f32x4){b, b, b, b};
  }

  int row0 = baseRow + l15;
  int row1 = row0 + 16;
  int r0c = (row0 < n) ? row0 : (n - 1);
  int r1c = (row1 < n) ? row1 : (n - 1);
  int x0 = xidx ? xidx[r0c] : r0c;
  int x1 = xidx ? xidx[r1c] : r1c;
  const float* a0p = agg + (size_t)r0c * HD;
  const float* a1p = agg + (size_t)r1c * HD;
  const float* x0p = xdst + (size_t)x0 * HD;
  const float* x1p = xdst + (size_t)x1 * HD;

  for (int ks = 0; ks < 8; ++ks) {
    const float* s0 = (ks < 4) ? (a0p + ks * 32 + kg * 8) : (x0p + (ks - 4) * 32 + kg * 8);
    const float* s1 = (ks < 4) ? (a1p + ks * 32 + kg * 8) : (x1p + (ks - 4) * 32 + kg * 8);
    f32x4 u0 = ((const f32x4*)s0)[0];
    f32x4 v0 = ((const f32x4*)s0)[1];
    f32x4 u1 = ((const f32x4*)s1)[0];
    f32x4 v1 = ((const f32x4*)s1)[1];
    bf16x8 ah0, al0, ah1, al1;
#pragma unroll
    for (int j = 0; j < 4; ++j) {
      unsigned short h;
      h = f2bf(u0[j]); ah0[j] = (short)h; al0[j] = (short)f2bf(u0[j] - bf2f(h));
      h = f2bf(v0[j]); ah0[j + 4] = (short)h; al0[j + 4] = (short)f2bf(v0[j] - bf2f(h));
      h = f2bf(u1[j]); ah1[j] = (short)h; al1[j] = (short)f2bf(u1[j] - bf2f(h));
      h = f2bf(v1[j]); ah1[j + 4] = (short)h; al1[j + 4] = (short)f2bf(v1[j] - bf2f(h));
    }
    const bf16x8* bhp = (const bf16x8*)Bh + (size_t)(ks * 8) * 64 + lane;
    const bf16x8* blp = (const bf16x8*)Bl + (size_t)(ks * 8) * 64 + lane;
#pragma unroll
    for (int cf = 0; cf < 8; ++cf) {
      bf16x8 bh = bhp[cf * 64];
      bf16x8 bl = blp[cf * 64];
      acc[0][cf] = __builtin_amdgcn_mfma_f32_16x16x32_bf16(ah0, bh, acc[0][cf], 0, 0, 0);
      acc[0][cf] = __builtin_amdgcn_mfma_f32_16x16x32_bf16(ah0, bl, acc[0][cf], 0, 0, 0);
      acc[0][cf] = __builtin_amdgcn_mfma_f32_16x16x32_bf16(al0, bh, acc[0][cf], 0, 0, 0);
      acc[1][cf] = __builtin_amdgcn_mfma_f32_16x16x32_bf16(ah1, bh, acc[1][cf], 0, 0, 0);
      acc[1][cf] = __builtin_amdgcn_mfma_f32_16x16x32_bf16(ah1, bl, acc[1][cf], 0, 0, 0);
      acc[1][cf] = __builtin_amdgcn_mfma_f32_16x16x32_bf16(al1, bh, acc[1][cf], 0, 0, 0);
    }
  }

  // epilogue: C layout col = lane&15, row = (lane>>4)*4 + reg
#pragma unroll
  for (int rf = 0; rf < 2; ++rf) {
    float ss[4] = {0.f, 0.f, 0.f, 0.f};
#pragma unroll
    for (int cf = 0; cf < 8; ++cf) {
#pragma unroll
      for (int rg = 0; rg < 4; ++rg) ss[rg] += acc[rf][cf][rg] * acc[rf][cf][rg];
    }
#pragma unroll
    for (int rg = 0; rg < 4; ++rg) {
#pragma unroll
      for (int m = 1; m < 16; m <<= 1) ss[rg] += __shfl_xor(ss[rg], m, 64);
    }
#pragma unroll
    for (int rg = 0; rg < 4; ++rg) {
      int row = baseRow + rf * 16 + kg * 4 + rg;
      if (row >= n) continue;
      float inv = 1.0f / fmaxf(sqrtf(ss[rg]), 1e-12f);
#pragma unroll
      for (int cf = 0; cf < 8; ++cf) {
        float v = acc[rf][cf][rg] * inv;
        if (leaky) v = (v > 0.f) ? v : 0.01f * v;
        int col = cf * 16 + l15;
        if (resid) v += resid[(size_t)row * HD + col];
        out[(size_t)row * HD + col] = v;
        if (outB) outB[(size_t)row * HD + col] = f2bf(v);
      }
    }
  }
}

// ---------------- classifier ----------------
__global__ __launch_bounds__(256) void k_classifier(
    const int* __restrict__ eli, int nL,
    const float* __restrict__ h3s, const float* __restrict__ h3t,
    float* __restrict__ out) {
  int w = (int)((blockIdx.x * 256 + threadIdx.x) >> 6);
  int lane = threadIdx.x & 63;
  if (w >= nL) return;
  int s = eli[w];
  int t = eli[nL + w];
  float2 a = ((const float2*)h3s)[(size_t)s * 64 + lane];
  float2 b = ((const float2*)h3t)[(size_t)t * 64 + lane];
  float p = a.x * b.x + a.y * b.y;
#pragma unroll
  for (int ofs = 32; ofs > 0; ofs >>= 1) p += __shfl_xor(p, ofs, 64);
  if (lane == 0) out[w] = p;
}

extern "C" void kernel_launch(void* const* d_in, const int* in_sizes, int n_in,
                              void* d_out, int out_size, void* d_ws, size_t ws_size,
                              hipStream_t stream) {
  (void)n_in;
  (void)out_size;
  const int* snid = (const int*)d_in[0];
  const int* tnid = (const int*)d_in[1];
  const int* ei = (const int*)d_in[2];
  const int* eli = (const int*)d_in[3];
  const float* semb = (const float*)d_in[4];
  const float* temb = (const float*)d_in[5];
  const float* w1l_bt = (const float*)d_in[6];
  const float* w1r_bt = (const float*)d_in[7];
  const float* w1l_tb = (const float*)d_in[8];
  const float* w1r_tb = (const float*)d_in[9];
  const float* w2l_bt = (const float*)d_in[10];
  const float* w2r_bt = (const float*)d_in[11];
  const float* w2l_tb = (const float*)d_in[12];
  const float* w2r_tb = (const float*)d_in[13];
  const float* b1_bt = (const float*)d_in[14];
  const float* b1_tb = (const float*)d_in[15];
  const float* b2_bt = (const float*)d_in[16];
  const float* b2_tb = (const float*)d_in[17];

  const int NS_ = in_sizes[0];
  const int NT_ = in_sizes[1];
  const int nE = in_sizes[2] / 2;
  const int nL = in_sizes[3] / 2;
  float* out = (float*)d_out;

  if (NS_ > 65535 || NT_ > 65535) return;  // packing assumption

  const int nbT = (NT_ + 63) >> 6;
  const int nbS = (NS_ + 63) >> 6;
  if (nbT > 800 || nbS > 800 || nbT + nbS > 1600) return;

  char* ws = (char*)d_ws;
  size_t o = 0;
  auto alloc = [&](size_t bytes) -> void* {
    void* p = ws + o;
    o = (o + bytes + 255) & ~(size_t)255;
    return p;
  };
  int* boffT = (int*)alloc(((size_t)nbT + 1) * 4);
  int* bcurT = (int*)alloc((size_t)nbT * 4);
  int* boffS = (int*)alloc(((size_t)nbS + 1) * 4);
  int* bcurS = (int*)alloc((size_t)nbS * 4);
  unsigned* ebufT = (unsigned*)alloc((size_t)nE * 4);
  unsigned* ebufS = (unsigned*)alloc((size_t)nE * 4);
  int* noffT = (int*)alloc(((size_t)NT_ + 1) * 4);
  int* noffS = (int*)alloc(((size_t)NS_ + 1) * 4);
  int* adjT = (int*)alloc((size_t)nE * 4);
  int* adjS = (int*)alloc((size_t)nE * 4);
  short* Bh1 = (short*)alloc(256 * HD * 2);
  short* Bl1 = (short*)alloc(256 * HD * 2);
  short* Bh2 = (short*)alloc(256 * HD * 2);
  short* Bl2 = (short*)alloc(256 * HD * 2);
  short* Bh3 = (short*)alloc(256 * HD * 2);
  short* Bl3 = (short*)alloc(256 * HD * 2);
  short* Bh4 = (short*)alloc(256 * HD * 2);
  short* Bl4 = (short*)alloc(256 * HD * 2);
  int nmax = imax(NS_, NT_);
  // bf16 tables: layer1 = gathered embeddings; reused for h1 bf16 copies
  unsigned short* bufX0 = (unsigned short*)alloc((size_t)nmax * HD * 2);  // xsB -> h1tB
  unsigned short* bufX1 = (unsigned short*)alloc((size_t)nmax * HD * 2);  // xtB -> h1sB
  float* aggA = (float*)alloc((size_t)nmax * HD * 4);  // T-side agg; later h3t
  float* aggB = (float*)alloc((size_t)nmax * HD * 4);  // S-side agg; later h3s
  float* h1s = (float*)alloc((size_t)NS_ * HD * 4);
  float* h1t = (float*)alloc((size_t)NT_ * HD * 4);
  if (o > ws_size) return;

  // ---- bucket sort -> per-node CSR (both directions) ----
  hipMemsetAsync(bcurT, 0, (size_t)nbT * 4, stream);
  hipMemsetAsync(bcurS, 0, (size_t)nbS * 4, stream);
  k_bhist<<<64, 256, 0, stream>>>(ei, nE, bcurT, nbT, bcurS, nbS);
  k_bscan<<<2, 1024, 0, stream>>>(bcurT, boffT, nbT, bcurS, boffS, nbS);
  k_bscatter<<<ceil_div(nE, SC_CH), 256, 0, stream>>>(ei, nE, bcurT, nbT, ebufT,
                                                      bcurS, nbS, ebufS);
  k_bsort<<<nbT, 256, 0, stream>>>(ebufT, boffT, noffT, adjT, NT_, nE);
  k_bsort<<<nbS, 256, 0, stream>>>(ebufS, boffS, noffS, adjS, NS_, nE);

  // ---- bf16 node-indexed feature tables (pre-applied snid/tnid lookup) ----
  k_cast_gather<<<ceil_div((NS_ + NT_) * 32, 256), 256, 0, stream>>>(
      semb, snid, bufX0, NS_, temb, tnid, bufX1, NT_);

  // ---- weight prep (fragment-ordered bf16 hi/lo) ----
  int wgrid = ceil_div(256 * HD, 256);
  k_build_pack<<<wgrid, 256, 0, stream>>>(w1l_bt, w1r_bt, Bh1, Bl1);
  k_build_pack<<<wgrid, 256, 0, stream>>>(w1l_tb, w1r_tb, Bh2, Bl2);
  k_build_pack<<<wgrid, 256, 0, stream>>>(w2l_bt, w2r_bt, Bh3, Bl3);
  k_build_pack<<<wgrid, 256, 0, stream>>>(w2l_tb, w2r_tb, Bh4, Bl4);

  int aggGrid = ceil_div(NT_ + NS_, 8);  // 2 nodes per wave, 4 waves per block

  // ---- layer 1 (dir T gathers x_s = bufX0; dir S gathers x_t = bufX1) ----
  k_agg_dual<<<aggGrid, 256, 0, stream>>>(bufX0, noffT, adjT, aggA, NT_,
                                          bufX1, noffS, adjS, aggB, NS_);
  // GEMM-T consumes bufX0-as-xsB? no: reads aggA + temb; bufX0 now dead -> h1tB
  k_gemm_mfma<<<ceil_div(NT_, 128), 256, 0, stream>>>(aggA, temb, tnid, Bh1, Bl1, b1_bt,
                                                      nullptr, h1t, bufX0, NT_, 1);
  k_gemm_mfma<<<ceil_div(NS_, 128), 256, 0, stream>>>(aggB, semb, snid, Bh2, Bl2, b1_tb,
                                                      nullptr, h1s, bufX1, NS_, 1);

  // ---- layer 2 (dir T gathers h1s = bufX1; dir S gathers h1t = bufX0) ----
  k_agg_dual<<<aggGrid, 256, 0, stream>>>(bufX1, noffT, adjT, aggA, NT_,
                                          bufX0, noffS, adjS, aggB, NS_);
  k_gemm_mfma<<<ceil_div(NT_, 128), 256, 0, stream>>>(aggA, h1t, nullptr, Bh3, Bl3, b2_bt,
                                                      h1t, aggA, nullptr, NT_, 0);
  k_gemm_mfma<<<ceil_div(NS_, 128), 256, 0, stream>>>(aggB, h1s, nullptr, Bh4, Bl4, b2_tb,
                                                      h1s, aggB, nullptr, NS_, 0);

  // ---- classifier ----
  k_classifier<<<ceil_div(nL, 4), 256, 0, stream>>>(eli, nL, aggB, aggA, out);
}

// Round 7
// 329.965 us; speedup vs baseline: 7.3263x; 1.0218x over previous
//
#include <hip/hip_runtime.h>
#include <cstdint>
#include <cstddef>

#define HD 128  // hidden channels

typedef __attribute__((ext_vector_type(8))) short bf16x8;
typedef __attribute__((ext_vector_type(4))) float f32x4;

static inline int ceil_div(int a, int b) { return (a + b - 1) / b; }
static inline int imax(int a, int b) { return a > b ? a : b; }

// f32 -> bf16 (RNE) as raw bits
__device__ __forceinline__ unsigned short f2bf(float f) {
  unsigned u = __float_as_uint(f);
  return (unsigned short)((u + 0x7FFFu + ((u >> 16) & 1u)) >> 16);
}
__device__ __forceinline__ float bf2f(unsigned short h) {
  return __uint_as_float(((unsigned)h) << 16);
}

// ============ bucket sort of edges (64 dst-nodes per bucket) ============
__global__ __launch_bounds__(256) void k_bhist(const int* __restrict__ ei, int nE,
                                               int* __restrict__ histT, int nbT,
                                               int* __restrict__ histS, int nbS) {
  __shared__ int h[1600];
  int nb = nbT + nbS;
  for (int i = threadIdx.x; i < nb; i += 256) h[i] = 0;
  __syncthreads();
  int stride = gridDim.x * 256;
  for (int e = blockIdx.x * 256 + threadIdx.x; e < nE; e += stride) {
    int s = ei[e];
    int t = ei[nE + e];
    atomicAdd(&h[t >> 6], 1);
    atomicAdd(&h[nbT + (s >> 6)], 1);
  }
  __syncthreads();
  for (int i = threadIdx.x; i < nb; i += 256) {
    int v = h[i];
    if (v) {
      if (i < nbT) atomicAdd(&histT[i], v);
      else atomicAdd(&histS[i - nbT], v);
    }
  }
}

__global__ __launch_bounds__(1024) void k_bscan(int* __restrict__ histA, int* __restrict__ offA, int nA,
                                                int* __restrict__ histB, int* __restrict__ offB, int nB) {
  int* hist = blockIdx.x ? histB : histA;
  int* off = blockIdx.x ? offB : offA;
  int n = blockIdx.x ? nB : nA;
  __shared__ int wsum[16];
  int tid = threadIdx.x;
  int lane = tid & 63;
  int wid = tid >> 6;
  int v = (tid < n) ? hist[tid] : 0;
  int x = v;
#pragma unroll
  for (int d = 1; d < 64; d <<= 1) {
    int y = __shfl_up(x, d, 64);
    if (lane >= d) x += y;
  }
  if (lane == 63) wsum[wid] = x;
  __syncthreads();
  if (wid == 0) {
    int s = (lane < 16) ? wsum[lane] : 0;
#pragma unroll
    for (int d = 1; d < 16; d <<= 1) {
      int y = __shfl_up(s, d, 64);
      if (lane >= d) s += y;
    }
    if (lane < 16) wsum[lane] = s;
  }
  __syncthreads();
  int wofs = (wid > 0) ? wsum[wid - 1] : 0;
  int exc = wofs + x - v;
  if (tid < n) {
    off[tid] = exc;
    hist[tid] = exc;  // cursor
  }
  if (tid == 0) off[n] = wsum[15];
}

#define SC_CH 2048
__global__ __launch_bounds__(256) void k_bscatter(const int* __restrict__ ei, int nE,
                                                  int* __restrict__ curT, int nbT,
                                                  unsigned* __restrict__ ebufT,
                                                  int* __restrict__ curS, int nbS,
                                                  unsigned* __restrict__ ebufS) {
  __shared__ unsigned epk[SC_CH];
  __shared__ int cntT[800], baseT[800], cntS[800], baseS[800];
  int tid = threadIdx.x;
  int e0 = blockIdx.x * SC_CH;
  for (int i = tid; i < nbT; i += 256) cntT[i] = 0;
  for (int i = tid; i < nbS; i += 256) cntS[i] = 0;
  for (int i = tid; i < SC_CH; i += 256) {
    int e = e0 + i;
    epk[i] = (e < nE) ? (((unsigned)ei[e] << 16) | (unsigned)ei[nE + e]) : 0xFFFFFFFFu;
  }
  __syncthreads();
  int rT[8], rS[8];
#pragma unroll
  for (int j = 0; j < 8; ++j) {
    int i = tid * 8 + j;
    unsigned p = epk[i];
    if (p != 0xFFFFFFFFu) {
      int t = (int)(p & 0xFFFFu);
      int s = (int)(p >> 16);
      rT[j] = atomicAdd(&cntT[t >> 6], 1);
      rS[j] = atomicAdd(&cntS[s >> 6], 1);
    }
  }
  __syncthreads();
  for (int b = tid; b < nbT; b += 256) baseT[b] = cntT[b] ? atomicAdd(&curT[b], cntT[b]) : 0;
  for (int b = tid; b < nbS; b += 256) baseS[b] = cntS[b] ? atomicAdd(&curS[b], cntS[b]) : 0;
  __syncthreads();
#pragma unroll
  for (int j = 0; j < 8; ++j) {
    int i = tid * 8 + j;
    unsigned p = epk[i];
    if (p != 0xFFFFFFFFu) {
      unsigned t = p & 0xFFFFu;
      unsigned s = p >> 16;
      ebufT[baseT[t >> 6] + rT[j]] = (s << 6) | (t & 63u);
      ebufS[baseS[s >> 6] + rS[j]] = (t << 6) | (s & 63u);
    }
  }
}

// ============ per-bucket counting sort -> per-node CSR ============
// adj entries are PRE-SHIFTED byte offsets into the bf16 feature table:
// adj[p] = src_id * 256 (= src_id << 8, row stride HD*2 bytes).
__global__ __launch_bounds__(256) void k_bsort(const unsigned* __restrict__ ebuf,
                                               const int* __restrict__ boff,
                                               int* __restrict__ noff,
                                               int* __restrict__ adj,
                                               int ndst, int nE) {
  __shared__ int cnt[64];
  __shared__ int pos[64];
  int b = blockIdx.x;
  int tid = threadIdx.x;
  if (tid < 64) cnt[tid] = 0;
  __syncthreads();
  int beg = boff[b], end = boff[b + 1];
  for (int k = beg + tid; k < end; k += 256) {
    atomicAdd(&cnt[ebuf[k] & 63u], 1);
  }
  __syncthreads();
  if (tid < 64) {
    int v = cnt[tid];
    int x = v;
#pragma unroll
    for (int d = 1; d < 64; d <<= 1) {
      int y = __shfl_up(x, d, 64);
      if (tid >= d) x += y;
    }
    int start = beg + x - v;
    pos[tid] = start;
    int node = (b << 6) + tid;
    if (node < ndst) noff[node] = start;
  }
  __syncthreads();
  for (int k = beg + tid; k < end; k += 256) {
    unsigned e = ebuf[k];
    int p = atomicAdd(&pos[e & 63u], 1);
    adj[p] = (int)((e >> 6) << 8);  // byte offset = src * 256
  }
  if (b == 0 && tid == 0) noff[ndst] = nE;
}

// ============ gather-cast: node-indexed bf16 feature tables ============
__global__ __launch_bounds__(256) void k_cast_gather(
    const float* __restrict__ embA, const int* __restrict__ mapA,
    unsigned short* __restrict__ outA, int nA,
    const float* __restrict__ embB, const int* __restrict__ mapB,
    unsigned short* __restrict__ outB, int nB) {
  int tid = blockIdx.x * 256 + threadIdx.x;
  int row = tid >> 5;
  int q = tid & 31;
  const float* src;
  unsigned short* dst;
  if (row < nA) {
    int r = mapA ? mapA[row] : row;
    src = embA + (size_t)r * HD;
    dst = outA + (size_t)row * HD;
  } else if (row < nA + nB) {
    int rr = row - nA;
    int r = mapB ? mapB[rr] : rr;
    src = embB + (size_t)r * HD;
    dst = outB + (size_t)rr * HD;
  } else {
    return;
  }
  float4 v = ((const float4*)src)[q];
  ushort4 o;
  o.x = f2bf(v.x);
  o.y = f2bf(v.y);
  o.z = f2bf(v.z);
  o.w = f2bf(v.w);
  ((ushort4*)dst)[q] = o;
}

// ============ scatter-mean: one node per wave, 2 edges per load slot ============
// lanes 0-31 read row of edge 2j (8 B = 4 bf16 ch each), lanes 32-63 edge 2j+1;
// adj indices / loop bounds are wave-uniform (readfirstlane -> SALU + saddr loads);
// full 16-edge iterations are mask-free; cross-half merge via shfl_xor(32).
__global__ __launch_bounds__(256) void k_agg_dual(
    const unsigned short* __restrict__ xA, const int* __restrict__ noffA,
    const int* __restrict__ adjA, float* __restrict__ aggA, int nA,
    const unsigned short* __restrict__ xB, const int* __restrict__ noffB,
    const int* __restrict__ adjB, float* __restrict__ aggB, int nB) {
  int w = (int)((blockIdx.x * 256 + threadIdx.x) >> 6);
  int lane = threadIdx.x & 63;
  int total = nA + nB;
  if (w >= total) return;
  const unsigned short* x;
  const int* adj;
  float* agg;
  int node, beg, end;
  if (w < nA) {
    x = xA; adj = adjA; agg = aggA; node = w;
    beg = noffA[w]; end = noffA[w + 1];
  } else {
    node = w - nA;
    x = xB; adj = adjB; agg = aggB;
    beg = noffB[node]; end = noffB[node + 1];
  }
  beg = __builtin_amdgcn_readfirstlane(beg);
  end = __builtin_amdgcn_readfirstlane(end);
  int d = end - beg;
  int h = (lane >> 5);                          // 0: even edge, 1: odd edge
  unsigned loff = (unsigned)((lane & 31) << 3); // byte offset within row

  float a0 = 0.f, a1 = 0.f, a2 = 0.f, a3 = 0.f;
  int fullIters = d >> 4;
  for (int it = 0; it < fullIters; ++it) {
    int base = beg + it * 16;
#pragma unroll
    for (int j = 0; j < 8; ++j) {
      int oa = __builtin_amdgcn_readfirstlane(adj[base + 2 * j]);
      int ob = __builtin_amdgcn_readfirstlane(adj[base + 2 * j + 1]);
      unsigned off = (unsigned)(h ? ob : oa) + loff;
      uint2 v = *(const uint2*)((const char*)x + off);
      a0 += __uint_as_float(v.x << 16);
      a1 += __uint_as_float(v.x & 0xFFFF0000u);
      a2 += __uint_as_float(v.y << 16);
      a3 += __uint_as_float(v.y & 0xFFFF0000u);
    }
  }
  if (d & 15) {
    int base = beg + fullIters * 16;
    int rem = d & 15;  // 1..15 valid slots in this iteration
#pragma unroll
    for (int j = 0; j < 8; ++j) {
      int ka = base + 2 * j;
      int kb = ka + 1;
      int kac = (2 * j < rem) ? ka : (end - 1);
      int kbc = (2 * j + 1 < rem) ? kb : (end - 1);
      int oa = __builtin_amdgcn_readfirstlane(adj[kac]);
      int ob = __builtin_amdgcn_readfirstlane(adj[kbc]);
      unsigned off = (unsigned)(h ? ob : oa) + loff;
      uint2 v = *(const uint2*)((const char*)x + off);
      float m = (2 * j + h < rem) ? 1.f : 0.f;
      a0 = fmaf(m, __uint_as_float(v.x << 16), a0);
      a1 = fmaf(m, __uint_as_float(v.x & 0xFFFF0000u), a1);
      a2 = fmaf(m, __uint_as_float(v.y << 16), a2);
      a3 = fmaf(m, __uint_as_float(v.y & 0xFFFF0000u), a3);
    }
  }
  a0 += __shfl_xor(a0, 32, 64);
  a1 += __shfl_xor(a1, 32, 64);
  a2 += __shfl_xor(a2, 32, 64);
  a3 += __shfl_xor(a3, 32, 64);
  if (lane < 32) {
    float inv = d ? 1.0f / (float)d : 0.0f;
    float4 r = make_float4(a0 * inv, a1 * inv, a2 * inv, a3 * inv);
    ((float4*)(agg + (size_t)node * HD))[lane] = r;
  }
}

// ============ weight prep: fragment-ordered bf16 hi/lo planes ============
__global__ void k_build_pack(const float* __restrict__ wl, const float* __restrict__ wr,
                             short* __restrict__ Bh, short* __restrict__ Bl) {
  int idx = blockIdx.x * blockDim.x + threadIdx.x;
  if (idx >= 256 * HD) return;
  int j = idx & 7;
  int lane = (idx >> 3) & 63;
  int cf = (idx >> 9) & 7;
  int ks = idx >> 12;
  int k = ks * 32 + (lane >> 4) * 8 + j;
  int col = cf * 16 + (lane & 15);
  float val = (k < HD) ? wl[col * HD + k] : wr[col * HD + (k - HD)];
  unsigned short hi = f2bf(val);
  unsigned short lo = f2bf(val - bf2f(hi));
  Bh[idx] = (short)hi;
  Bl[idx] = (short)lo;
}

// ============ MFMA GEMM (split-bf16 x3) + bias + L2-norm + leaky/resid ============
__global__ __launch_bounds__(256) void k_gemm_mfma(
    const float* __restrict__ agg,
    const float* __restrict__ xdst,
    const int* __restrict__ xidx,
    const short* __restrict__ Bh, const short* __restrict__ Bl,
    const float* __restrict__ bias,
    const float* __restrict__ resid,
    float* __restrict__ out,
    unsigned short* __restrict__ outB,
    int n, int leaky) {
  int t = threadIdx.x;
  int lane = t & 63;
  int wv = t >> 6;
  int l15 = lane & 15;
  int kg = lane >> 4;  // 0..3
  int baseRow = blockIdx.x * 128 + wv * 32;

  f32x4 acc[2][8];
#pragma unroll
  for (int cf = 0; cf < 8; ++cf) {
    float b = bias[cf * 16 + l15];
    acc[0][cf] = (f32x4){b, b, b, b};
    acc[1][cf] = (f32x4){b, b, b, b};
  }

  int row0 = baseRow + l15;
  int row1 = row0 + 16;
  int r0c = (row0 < n) ? row0 : (n - 1);
  int r1c = (row1 < n) ? row1 : (n - 1);
  int x0 = xidx ? xidx[r0c] : r0c;
  int x1 = xidx ? xidx[r1c] : r1c;
  const float* a0p = agg + (size_t)r0c * HD;
  const float* a1p = agg + (size_t)r1c * HD;
  const float* x0p = xdst + (size_t)x0 * HD;
  const float* x1p = xdst + (size_t)x1 * HD;

  for (int ks = 0; ks < 8; ++ks) {
    const float* s0 = (ks < 4) ? (a0p + ks * 32 + kg * 8) : (x0p + (ks - 4) * 32 + kg * 8);
    const float* s1 = (ks < 4) ? (a1p + ks * 32 + kg * 8) : (x1p + (ks - 4) * 32 + kg * 8);
    f32x4 u0 = ((const f32x4*)s0)[0];
    f32x4 v0 = ((const f32x4*)s0)[1];
    f32x4 u1 = ((const f32x4*)s1)[0];
    f32x4 v1 = ((const f32x4*)s1)[1];
    bf16x8 ah0, al0, ah1, al1;
#pragma unroll
    for (int j = 0; j < 4; ++j) {
      unsigned short h;
      h = f2bf(u0[j]); ah0[j] = (short)h; al0[j] = (short)f2bf(u0[j] - bf2f(h));
      h = f2bf(v0[j]); ah0[j + 4] = (short)h; al0[j + 4] = (short)f2bf(v0[j] - bf2f(h));
      h = f2bf(u1[j]); ah1[j] = (short)h; al1[j] = (short)f2bf(u1[j] - bf2f(h));
      h = f2bf(v1[j]); ah1[j + 4] = (short)h; al1[j + 4] = (short)f2bf(v1[j] - bf2f(h));
    }
    const bf16x8* bhp = (const bf16x8*)Bh + (size_t)(ks * 8) * 64 + lane;
    const bf16x8* blp = (const bf16x8*)Bl + (size_t)(ks * 8) * 64 + lane;
#pragma unroll
    for (int cf = 0; cf < 8; ++cf) {
      bf16x8 bh = bhp[cf * 64];
      bf16x8 bl = blp[cf * 64];
      acc[0][cf] = __builtin_amdgcn_mfma_f32_16x16x32_bf16(ah0, bh, acc[0][cf], 0, 0, 0);
      acc[0][cf] = __builtin_amdgcn_mfma_f32_16x16x32_bf16(ah0, bl, acc[0][cf], 0, 0, 0);
      acc[0][cf] = __builtin_amdgcn_mfma_f32_16x16x32_bf16(al0, bh, acc[0][cf], 0, 0, 0);
      acc[1][cf] = __builtin_amdgcn_mfma_f32_16x16x32_bf16(ah1, bh, acc[1][cf], 0, 0, 0);
      acc[1][cf] = __builtin_amdgcn_mfma_f32_16x16x32_bf16(ah1, bl, acc[1][cf], 0, 0, 0);
      acc[1][cf] = __builtin_amdgcn_mfma_f32_16x16x32_bf16(al1, bh, acc[1][cf], 0, 0, 0);
    }
  }

  // epilogue: C layout col = lane&15, row = (lane>>4)*4 + reg
#pragma unroll
  for (int rf = 0; rf < 2; ++rf) {
    float ss[4] = {0.f, 0.f, 0.f, 0.f};
#pragma unroll
    for (int cf = 0; cf < 8; ++cf) {
#pragma unroll
      for (int rg = 0; rg < 4; ++rg) ss[rg] += acc[rf][cf][rg] * acc[rf][cf][rg];
    }
#pragma unroll
    for (int rg = 0; rg < 4; ++rg) {
#pragma unroll
      for (int m = 1; m < 16; m <<= 1) ss[rg] += __shfl_xor(ss[rg], m, 64);
    }
#pragma unroll
    for (int rg = 0; rg < 4; ++rg) {
      int row = baseRow + rf * 16 + kg * 4 + rg;
      if (row >= n) continue;
      float inv = 1.0f / fmaxf(sqrtf(ss[rg]), 1e-12f);
#pragma unroll
      for (int cf = 0; cf < 8; ++cf) {
        float v = acc[rf][cf][rg] * inv;
        if (leaky) v = (v > 0.f) ? v : 0.01f * v;
        int col = cf * 16 + l15;
        if (resid) v += resid[(size_t)row * HD + col];
        out[(size_t)row * HD + col] = v;
        if (outB) outB[(size_t)row * HD + col] = f2bf(v);
      }
    }
  }
}

// ---------------- classifier ----------------
__global__ __launch_bounds__(256) void k_classifier(
    const int* __restrict__ eli, int nL,
    const float* __restrict__ h3s, const float* __restrict__ h3t,
    float* __restrict__ out) {
  int w = (int)((blockIdx.x * 256 + threadIdx.x) >> 6);
  int lane = threadIdx.x & 63;
  if (w >= nL) return;
  int s = eli[w];
  int t = eli[nL + w];
  float2 a = ((const float2*)h3s)[(size_t)s * 64 + lane];
  float2 b = ((const float2*)h3t)[(size_t)t * 64 + lane];
  float p = a.x * b.x + a.y * b.y;
#pragma unroll
  for (int ofs = 32; ofs > 0; ofs >>= 1) p += __shfl_xor(p, ofs, 64);
  if (lane == 0) out[w] = p;
}

extern "C" void kernel_launch(void* const* d_in, const int* in_sizes, int n_in,
                              void* d_out, int out_size, void* d_ws, size_t ws_size,
                              hipStream_t stream) {
  (void)n_in;
  (void)out_size;
  const int* snid = (const int*)d_in[0];
  const int* tnid = (const int*)d_in[1];
  const int* ei = (const int*)d_in[2];
  const int* eli = (const int*)d_in[3];
  const float* semb = (const float*)d_in[4];
  const float* temb = (const float*)d_in[5];
  const float* w1l_bt = (const float*)d_in[6];
  const float* w1r_bt = (const float*)d_in[7];
  const float* w1l_tb = (const float*)d_in[8];
  const float* w1r_tb = (const float*)d_in[9];
  const float* w2l_bt = (const float*)d_in[10];
  const float* w2r_bt = (const float*)d_in[11];
  const float* w2l_tb = (const float*)d_in[12];
  const float* w2r_tb = (const float*)d_in[13];
  const float* b1_bt = (const float*)d_in[14];
  const float* b1_tb = (const float*)d_in[15];
  const float* b2_bt = (const float*)d_in[16];
  const float* b2_tb = (const float*)d_in[17];

  const int NS_ = in_sizes[0];
  const int NT_ = in_sizes[1];
  const int nE = in_sizes[2] / 2;
  const int nL = in_sizes[3] / 2;
  float* out = (float*)d_out;

  if (NS_ > 65535 || NT_ > 65535) return;  // packing assumption

  const int nbT = (NT_ + 63) >> 6;
  const int nbS = (NS_ + 63) >> 6;
  if (nbT > 800 || nbS > 800 || nbT + nbS > 1600) return;

  char* ws = (char*)d_ws;
  size_t o = 0;
  auto alloc = [&](size_t bytes) -> void* {
    void* p = ws + o;
    o = (o + bytes + 255) & ~(size_t)255;
    return p;
  };
  int* boffT = (int*)alloc(((size_t)nbT + 1) * 4);
  int* bcurT = (int*)alloc((size_t)nbT * 4);
  int* boffS = (int*)alloc(((size_t)nbS + 1) * 4);
  int* bcurS = (int*)alloc((size_t)nbS * 4);
  unsigned* ebufT = (unsigned*)alloc((size_t)nE * 4);
  unsigned* ebufS = (unsigned*)alloc((size_t)nE * 4);
  int* noffT = (int*)alloc(((size_t)NT_ + 1) * 4);
  int* noffS = (int*)alloc(((size_t)NS_ + 1) * 4);
  int* adjT = (int*)alloc((size_t)nE * 4);
  int* adjS = (int*)alloc((size_t)nE * 4);
  short* Bh1 = (short*)alloc(256 * HD * 2);
  short* Bl1 = (short*)alloc(256 * HD * 2);
  short* Bh2 = (short*)alloc(256 * HD * 2);
  short* Bl2 = (short*)alloc(256 * HD * 2);
  short* Bh3 = (short*)alloc(256 * HD * 2);
  short* Bl3 = (short*)alloc(256 * HD * 2);
  short* Bh4 = (short*)alloc(256 * HD * 2);
  short* Bl4 = (short*)alloc(256 * HD * 2);
  int nmax = imax(NS_, NT_);
  // bf16 tables: layer1 = gathered embeddings; reused for h1 bf16 copies
  unsigned short* bufX0 = (unsigned short*)alloc((size_t)nmax * HD * 2);  // xsB -> h1tB
  unsigned short* bufX1 = (unsigned short*)alloc((size_t)nmax * HD * 2);  // xtB -> h1sB
  float* aggA = (float*)alloc((size_t)nmax * HD * 4);  // T-side agg; later h3t
  float* aggB = (float*)alloc((size_t)nmax * HD * 4);  // S-side agg; later h3s
  float* h1s = (float*)alloc((size_t)NS_ * HD * 4);
  float* h1t = (float*)alloc((size_t)NT_ * HD * 4);
  if (o > ws_size) return;

  // ---- bucket sort -> per-node CSR (both directions) ----
  hipMemsetAsync(bcurT, 0, (size_t)nbT * 4, stream);
  hipMemsetAsync(bcurS, 0, (size_t)nbS * 4, stream);
  k_bhist<<<64, 256, 0, stream>>>(ei, nE, bcurT, nbT, bcurS, nbS);
  k_bscan<<<2, 1024, 0, stream>>>(bcurT, boffT, nbT, bcurS, boffS, nbS);
  k_bscatter<<<ceil_div(nE, SC_CH), 256, 0, stream>>>(ei, nE, bcurT, nbT, ebufT,
                                                      bcurS, nbS, ebufS);
  k_bsort<<<nbT, 256, 0, stream>>>(ebufT, boffT, noffT, adjT, NT_, nE);
  k_bsort<<<nbS, 256, 0, stream>>>(ebufS, boffS, noffS, adjS, NS_, nE);

  // ---- bf16 node-indexed feature tables (pre-applied snid/tnid lookup) ----
  k_cast_gather<<<ceil_div((NS_ + NT_) * 32, 256), 256, 0, stream>>>(
      semb, snid, bufX0, NS_, temb, tnid, bufX1, NT_);

  // ---- weight prep (fragment-ordered bf16 hi/lo) ----
  int wgrid = ceil_div(256 * HD, 256);
  k_build_pack<<<wgrid, 256, 0, stream>>>(w1l_bt, w1r_bt, Bh1, Bl1);
  k_build_pack<<<wgrid, 256, 0, stream>>>(w1l_tb, w1r_tb, Bh2, Bl2);
  k_build_pack<<<wgrid, 256, 0, stream>>>(w2l_bt, w2r_bt, Bh3, Bl3);
  k_build_pack<<<wgrid, 256, 0, stream>>>(w2l_tb, w2r_tb, Bh4, Bl4);

  int aggGrid = ceil_div(NT_ + NS_, 4);  // 1 node per wave, 4 waves per block

  // ---- layer 1 (dir T gathers x_s = bufX0; dir S gathers x_t = bufX1) ----
  k_agg_dual<<<aggGrid, 256, 0, stream>>>(bufX0, noffT, adjT, aggA, NT_,
                                          bufX1, noffS, adjS, aggB, NS_);
  k_gemm_mfma<<<ceil_div(NT_, 128), 256, 0, stream>>>(aggA, temb, tnid, Bh1, Bl1, b1_bt,
                                                      nullptr, h1t, bufX0, NT_, 1);
  k_gemm_mfma<<<ceil_div(NS_, 128), 256, 0, stream>>>(aggB, semb, snid, Bh2, Bl2, b1_tb,
                                                      nullptr, h1s, bufX1, NS_, 1);

  // ---- layer 2 (dir T gathers h1s = bufX1; dir S gathers h1t = bufX0) ----
  k_agg_dual<<<aggGrid, 256, 0, stream>>>(bufX1, noffT, adjT, aggA, NT_,
                                          bufX0, noffS, adjS, aggB, NS_);
  k_gemm_mfma<<<ceil_div(NT_, 128), 256, 0, stream>>>(aggA, h1t, nullptr, Bh3, Bl3, b2_bt,
                                                      h1t, aggA, nullptr, NT_, 0);
  k_gemm_mfma<<<ceil_div(NS_, 128), 256, 0, stream>>>(aggB, h1s, nullptr, Bh4, Bl4, b2_tb,
                                                      h1s, aggB, nullptr, NS_, 0);

  // ---- classifier ----
  k_classifier<<<ceil_div(nL, 4), 256, 0, stream>>>(eli, nL, aggB, aggA, out);
}